// Round 1
// baseline (11750.970 us; speedup 1.0000x reference)
//
#include <hip/hip_runtime.h>

// ---------------------------------------------------------------------------
// ViT-Tiny + SAT elevation fusion, fp32 correctness-first implementation.
// B=128, S=197, D=192, depth=12, heads=3 (hd=64), MLP=768.
// All GEMM shapes divide the 64x64x16 tile exactly -> no bounds checks.
// ---------------------------------------------------------------------------

#define BATCH 128
#define SEQ 197
#define BS_ROWS (BATCH * SEQ)          // 25216
#define DMODEL 192
#define NPATCH 196
#define MROWS_PATCH (BATCH * NPATCH)   // 25088
#define KPATCH 768
#define MLPDIM 768
#define DEPTH 12

__device__ __forceinline__ float wredSum(float v) {
#pragma unroll
  for (int o = 32; o > 0; o >>= 1) v += __shfl_xor(v, o, 64);
  return v;
}
__device__ __forceinline__ float wredMax(float v) {
#pragma unroll
  for (int o = 32; o > 0; o >>= 1) v = fmaxf(v, __shfl_xor(v, o, 64));
  return v;
}

// ---------------------------------------------------------------------------
// Elevation weight: mean over x_g_norm[b] (3136 elems) -> bisect+interp -> w[b]
// ---------------------------------------------------------------------------
__global__ __launch_bounds__(256) void eleva_w_kernel(const float* __restrict__ xg,
                                                      float* __restrict__ wout) {
  const int b = blockIdx.x;
  const float* p = xg + (size_t)b * 3136;
  float s = 0.f;
  for (int i = threadIdx.x; i < 3136; i += 256) s += p[i];
  __shared__ float partial[4];
  s = wredSum(s);
  if ((threadIdx.x & 63) == 0) partial[threadIdx.x >> 6] = s;
  __syncthreads();
  if (threadIdx.x == 0) {
    float m = (partial[0] + partial[1] + partial[2] + partial[3]) / 3136.f;
    int idx = 0;
#pragma unroll
    for (int i = 0; i < 10; i++) {
      float pv = 0.1f * (float)(i + 1);
      if (pv < m) idx = i + 1;          // searchsorted 'left': count of elems < m
    }
    if (idx > 9) idx = 9;               // clip
    float wv;
    if (idx == 9) {
      wv = 9.f;
    } else {
      float hi = 0.1f * (float)(idx + 1);
      float lo = (idx == 0) ? 0.f : 0.1f * (float)idx;
      wv = (float)idx - (hi - m) / (hi - lo);
    }
    wout[b] = wv / 10.f;
  }
}

// ---------------------------------------------------------------------------
// im2col for the patch conv: col[row=b*196+p][k=c*256+i*16+j] = x[b,c,py*16+i,px*16+j]
// ---------------------------------------------------------------------------
__global__ __launch_bounds__(256) void im2col_kernel(const float* __restrict__ x,
                                                     float* __restrict__ col) {
  const int i = blockIdx.x * 256 + threadIdx.x;
  if (i >= MROWS_PATCH * KPATCH) return;
  const int k = i % KPATCH, row = i / KPATCH;
  const int b = row / NPATCH, p = row % NPATCH;
  const int py = p / 14, px = p % 14;
  const int c = k >> 8, r = (k >> 4) & 15, cc = k & 15;
  col[i] = x[(((size_t)b * 3 + c) * 224 + (py * 16 + r)) * 224 + (px * 16 + cc)];
}

// ---------------------------------------------------------------------------
// Assemble tokens: H[b,0,:] = cls+pos[0]; H[b,1+p,:] = tok_raw[b*196+p] + pos[1+p]
// (patch_b already folded into GEMM bias)
// ---------------------------------------------------------------------------
__global__ __launch_bounds__(256) void assemble_kernel(const float* __restrict__ tok_raw,
                                                       const float* __restrict__ cls,
                                                       const float* __restrict__ pos,
                                                       float* __restrict__ H) {
  const int i = blockIdx.x * 256 + threadIdx.x;
  if (i >= BS_ROWS * DMODEL) return;
  const int d = i % DMODEL, row = i / DMODEL;
  const int b = row / SEQ, s = row % SEQ;
  float v;
  if (s == 0)
    v = cls[d] + pos[d];
  else
    v = tok_raw[(size_t)(b * NPATCH + s - 1) * DMODEL + d] + pos[(size_t)s * DMODEL + d];
  H[i] = v;
}

// ---------------------------------------------------------------------------
// SAT: project the per-batch elevation vector through wq/wk/wv (tiny GEMVs)
// ---------------------------------------------------------------------------
__global__ __launch_bounds__(256) void ele_proj_kernel(
    const float* __restrict__ ele_emb, const float* __restrict__ wq, const float* __restrict__ bq,
    const float* __restrict__ wk, const float* __restrict__ bk,
    const float* __restrict__ wv, const float* __restrict__ bv,
    const float* __restrict__ wvec, float* __restrict__ eq, float* __restrict__ ek,
    float* __restrict__ ev) {
  const int b = blockIdx.x, t = threadIdx.x;
  __shared__ float es[DMODEL];
  if (t < DMODEL) es[t] = ele_emb[t] * wvec[b];
  __syncthreads();
  float aq = bq[t], ak = bk[t], av = bv[t];
  for (int d = 0; d < DMODEL; d++) {
    const float e = es[d];
    aq += e * wq[d * 256 + t];
    ak += e * wk[d * 256 + t];
    av += e * wv[d * 256 + t];
  }
  eq[b * 256 + t] = aq;
  ek[b * 256 + t] = ak;
  ev[b * 256 + t] = av;
}

// ---------------------------------------------------------------------------
// SAT 2-key attention mix. One thread per (token, head): 8 heads, 32 dims each.
// Output o256 = sum over both queries of per-head attention outputs.
// ---------------------------------------------------------------------------
__global__ __launch_bounds__(256) void sat_mix_kernel(
    const float* __restrict__ qt, const float* __restrict__ kt, const float* __restrict__ vt,
    const float* __restrict__ eq, const float* __restrict__ ek, const float* __restrict__ ev,
    float* __restrict__ o256) {
  const int gid = blockIdx.x * 256 + threadIdx.x;
  const int tok = gid >> 3, h = gid & 7;
  if (tok >= BS_ROWS) return;
  const int b = tok / SEQ;
  const float* qp = qt + (size_t)tok * 256 + h * 32;
  const float* kp = kt + (size_t)tok * 256 + h * 32;
  const float* vp = vt + (size_t)tok * 256 + h * 32;
  const float* eqp = eq + b * 256 + h * 32;
  const float* ekp = ek + b * 256 + h * 32;
  const float* evp = ev + b * 256 + h * 32;
  float s00 = 0.f, s01 = 0.f, s10 = 0.f, s11 = 0.f;
#pragma unroll 8
  for (int d = 0; d < 32; d++) {
    const float q_ = qp[d], k_ = kp[d], eq_ = eqp[d], ek_ = ekp[d];
    s00 += q_ * k_;
    s01 += q_ * ek_;
    s10 += eq_ * k_;
    s11 += eq_ * ek_;
  }
  const float sc = 0.17677669529663687f;  // 1/sqrt(32)
  s00 *= sc; s01 *= sc; s10 *= sc; s11 *= sc;
  const float m0 = fmaxf(s00, s01), m1 = fmaxf(s10, s11);
  const float e00 = __expf(s00 - m0), e01 = __expf(s01 - m0);
  const float e10 = __expf(s10 - m1), e11 = __expf(s11 - m1);
  const float w0 = e00 / (e00 + e01) + e10 / (e10 + e11);
  const float w1 = e01 / (e00 + e01) + e11 / (e10 + e11);
  float* op = o256 + (size_t)tok * 256 + h * 32;
#pragma unroll 8
  for (int d = 0; d < 32; d++) op[d] = w0 * vp[d] + w1 * evp[d];
}

// ---------------------------------------------------------------------------
// Generic fp32 GEMM, BM=BN=64, BK=16, 256 threads, 4x4 micro-tile.
// BLAYOUT: 0 = B row-major [K,N] (NN), 1 = B row-major [N,K] (NT -> A@B^T).
// EPI: 0 = acc + bias*bias_scale; 1 = res + acc + bias; 2 = gelu_exact(acc+bias)
// Requires M%64==0, N%64==0, K%16==0 (true for every call here).
// ---------------------------------------------------------------------------
template <int BLAYOUT, int EPI>
__global__ __launch_bounds__(256) void gemm64(const float* __restrict__ A,
                                              const float* __restrict__ B,
                                              const float* __restrict__ bias,
                                              const float* res, float* C, int M, int N,
                                              int K, float bias_scale) {
  __shared__ float As[16][68];
  __shared__ float Bs[16][68];
  const int tid = threadIdx.x;
  const int m0 = blockIdx.x * 64, n0 = blockIdx.y * 64;
  const int tx = tid & 15, ty = tid >> 4;
  const int la_r = tid >> 2, la_k = (tid & 3) << 2;
  float acc[4][4] = {{0.f}};
  for (int k0 = 0; k0 < K; k0 += 16) {
    const float4 av = *(const float4*)(A + (size_t)(m0 + la_r) * K + (k0 + la_k));
    As[la_k + 0][la_r] = av.x;
    As[la_k + 1][la_r] = av.y;
    As[la_k + 2][la_r] = av.z;
    As[la_k + 3][la_r] = av.w;
    if (BLAYOUT == 0) {
      const float4 bv = *(const float4*)(B + (size_t)(k0 + ty) * N + (n0 + tx * 4));
      *(float4*)&Bs[ty][tx * 4] = bv;
    } else {
      const float4 bv = *(const float4*)(B + (size_t)(n0 + la_r) * K + (k0 + la_k));
      Bs[la_k + 0][la_r] = bv.x;
      Bs[la_k + 1][la_r] = bv.y;
      Bs[la_k + 2][la_r] = bv.z;
      Bs[la_k + 3][la_r] = bv.w;
    }
    __syncthreads();
#pragma unroll
    for (int kk = 0; kk < 16; kk++) {
      const float4 a4 = *(const float4*)&As[kk][ty * 4];
      const float4 b4 = *(const float4*)&Bs[kk][tx * 4];
      const float a_[4] = {a4.x, a4.y, a4.z, a4.w};
      const float b_[4] = {b4.x, b4.y, b4.z, b4.w};
#pragma unroll
      for (int i = 0; i < 4; i++)
#pragma unroll
        for (int j = 0; j < 4; j++) acc[i][j] += a_[i] * b_[j];
    }
    __syncthreads();
  }
  float bvals[4];
#pragma unroll
  for (int j = 0; j < 4; j++) bvals[j] = bias[n0 + tx * 4 + j] * bias_scale;
#pragma unroll
  for (int i = 0; i < 4; i++) {
    const size_t m = m0 + ty * 4 + i;
    float v[4];
#pragma unroll
    for (int j = 0; j < 4; j++) {
      float t = acc[i][j] + bvals[j];
      if (EPI == 2) t = 0.5f * t * (1.0f + erff(t * 0.70710678118654752f));
      v[j] = t;
    }
    if (EPI == 1) {
      const float4 rv = *(const float4*)(res + m * N + n0 + tx * 4);
      v[0] += rv.x; v[1] += rv.y; v[2] += rv.z; v[3] += rv.w;
    }
    *(float4*)(C + m * N + n0 + tx * 4) = make_float4(v[0], v[1], v[2], v[3]);
  }
}

// ---------------------------------------------------------------------------
// LayerNorm over rows of 192 (one wave per row, 3 elems/lane)
// ---------------------------------------------------------------------------
__global__ __launch_bounds__(256) void ln_kernel(const float* __restrict__ X,
                                                 const float* __restrict__ g,
                                                 const float* __restrict__ bta,
                                                 float* __restrict__ Y, int nrows) {
  const int w = threadIdx.x >> 6, lane = threadIdx.x & 63;
  const int row = blockIdx.x * 4 + w;
  if (row >= nrows) return;
  const float* x = X + (size_t)row * DMODEL;
  const float x0 = x[lane], x1 = x[lane + 64], x2 = x[lane + 128];
  const float m = wredSum(x0 + x1 + x2) * (1.f / 192.f);
  const float d0 = x0 - m, d1 = x1 - m, d2 = x2 - m;
  const float v = wredSum(d0 * d0 + d1 * d1 + d2 * d2) * (1.f / 192.f);
  const float inv = rsqrtf(v + 1e-5f);
  float* y = Y + (size_t)row * DMODEL;
  y[lane] = d0 * inv * g[lane] + bta[lane];
  y[lane + 64] = d1 * inv * g[lane + 64] + bta[lane + 64];
  y[lane + 128] = d2 * inv * g[lane + 128] + bta[lane + 128];
}

// Final LN applied only to the cls row of each batch -> out[b, :]
__global__ __launch_bounds__(256) void final_ln_kernel(const float* __restrict__ H,
                                                       const float* __restrict__ g,
                                                       const float* __restrict__ bta,
                                                       float* __restrict__ out) {
  const int w = threadIdx.x >> 6, lane = threadIdx.x & 63;
  const int bi = blockIdx.x * 4 + w;
  if (bi >= BATCH) return;
  const float* x = H + (size_t)bi * SEQ * DMODEL;
  const float x0 = x[lane], x1 = x[lane + 64], x2 = x[lane + 128];
  const float m = wredSum(x0 + x1 + x2) * (1.f / 192.f);
  const float d0 = x0 - m, d1 = x1 - m, d2 = x2 - m;
  const float v = wredSum(d0 * d0 + d1 * d1 + d2 * d2) * (1.f / 192.f);
  const float inv = rsqrtf(v + 1e-5f);
  float* y = out + (size_t)bi * DMODEL;
  y[lane] = d0 * inv * g[lane] + bta[lane];
  y[lane + 64] = d1 * inv * g[lane + 64] + bta[lane + 64];
  y[lane + 128] = d2 * inv * g[lane + 128] + bta[lane + 128];
}

// ---------------------------------------------------------------------------
// Fused multi-head attention, one block per (batch, head). 8 waves, K/V in LDS.
// K rows XOR-swizzled at float4 granularity (row&7) to break the 256B-row
// bank-conflict pattern (cdna guide §6 G4). V padded to 65 (per-lane column
// reads, conflict-free). Softmax wave-parallel across 197 keys.
// ---------------------------------------------------------------------------
__global__ __launch_bounds__(512) void attn_kernel(const float* __restrict__ qkv,
                                                   float* __restrict__ out) {
  const int bh = blockIdx.x;
  const int b = bh / 3, h = bh % 3;
  const size_t row0 = (size_t)b * SEQ;
  __shared__ float Ks[SEQ * 64];
  __shared__ float Vs[SEQ * 65];
  __shared__ float qs[8][64];
  __shared__ float ps[8][200];
  const int tid = threadIdx.x, lane = tid & 63, w = tid >> 6;
  for (int idx = tid; idx < SEQ * 64; idx += 512) {
    const int kk = idx >> 6, d = idx & 63;
    const float* base = qkv + (row0 + kk) * 576 + h * 64 + d;
    Ks[kk * 64 + ((((d >> 2) ^ (kk & 7))) << 2) + (d & 3)] = base[192];
    Vs[kk * 65 + d] = base[384];
  }
  __syncthreads();
  for (int q0 = 0; q0 < SEQ; q0 += 8) {
    const int q = q0 + w;
    if (q < SEQ) {  // wave-uniform branch
      qs[w][lane] = qkv[(row0 + q) * 576 + h * 64 + lane];
      float scv[4];
#pragma unroll
      for (int j = 0; j < 4; j++) {
        const int kk = lane + j * 64;
        if (kk < SEQ) {
          const float* krow = &Ks[kk * 64];
          const int sw = kk & 7;
          float acc = 0.f;
#pragma unroll
          for (int d4 = 0; d4 < 16; d4++) {
            const float4 qv = *(const float4*)&qs[w][d4 << 2];
            const float4 kv = *(const float4*)&krow[(d4 ^ sw) << 2];
            acc += qv.x * kv.x + qv.y * kv.y + qv.z * kv.z + qv.w * kv.w;
          }
          scv[j] = acc * 0.125f;  // 64^-0.5
        } else {
          scv[j] = -INFINITY;
        }
      }
      float mx = fmaxf(fmaxf(scv[0], scv[1]), fmaxf(scv[2], scv[3]));
      mx = wredMax(mx);
      float se = 0.f;
#pragma unroll
      for (int j = 0; j < 4; j++) {
        const int kk = lane + j * 64;
        if (kk < SEQ) {
          const float e = __expf(scv[j] - mx);
          scv[j] = e;
          se += e;
        }
      }
      se = wredSum(se);
      const float inv = 1.f / se;
#pragma unroll
      for (int j = 0; j < 4; j++) {
        const int kk = lane + j * 64;
        if (kk < SEQ) ps[w][kk] = scv[j] * inv;
      }
      float acc = 0.f;
      for (int k = 0; k < SEQ; k++) acc += ps[w][k] * Vs[k * 65 + lane];
      out[(row0 + q) * DMODEL + h * 64 + lane] = acc;
    }
  }
}

// ---------------------------------------------------------------------------
extern "C" void kernel_launch(void* const* d_in, const int* in_sizes, int n_in,
                              void* d_out, int out_size, void* d_ws, size_t ws_size,
                              hipStream_t stream) {
  const float* x       = (const float*)d_in[0];
  const float* xg      = (const float*)d_in[1];
  const float* patch_w = (const float*)d_in[2];
  const float* patch_b = (const float*)d_in[3];
  const float* cls_tok = (const float*)d_in[4];
  const float* pos_emb = (const float*)d_in[5];
  const float* ele_emb = (const float*)d_in[6];
  const float* sat_wq  = (const float*)d_in[7];
  const float* sat_bq  = (const float*)d_in[8];
  const float* sat_wk  = (const float*)d_in[9];
  const float* sat_bk  = (const float*)d_in[10];
  const float* sat_wv  = (const float*)d_in[11];
  const float* sat_bv  = (const float*)d_in[12];
  const float* sat_wo  = (const float*)d_in[13];
  const float* sat_bo  = (const float*)d_in[14];
  const float* ln1_g   = (const float*)d_in[15];
  const float* ln1_b   = (const float*)d_in[16];
  const float* qkv_w   = (const float*)d_in[17];
  const float* qkv_b   = (const float*)d_in[18];
  const float* proj_w  = (const float*)d_in[19];
  const float* proj_b  = (const float*)d_in[20];
  const float* ln2_g   = (const float*)d_in[21];
  const float* ln2_b   = (const float*)d_in[22];
  const float* fc1_w   = (const float*)d_in[23];
  const float* fc1_b   = (const float*)d_in[24];
  const float* fc2_w   = (const float*)d_in[25];
  const float* fc2_b   = (const float*)d_in[26];
  const float* norm_g  = (const float*)d_in[27];
  const float* norm_b  = (const float*)d_in[28];
  float* out = (float*)d_out;
  float* ws = (float*)d_ws;

  // Workspace layout (floats). Total = 43,671,808 floats ~= 167 MiB.
  float* W_ELE = ws;                       // 128
  float* EQ = ws + 256;                    // 3 x 32768
  float* EK = EQ + 32768;
  float* EV = EK + 32768;
  float* H = ws + 98560;                   // 25216*192
  float* Y = H + 4841472;                  // 25216*192
  float* RA = Y + 4841472;                 // region A: 19,365,888 floats
  float* RB = RA + 19365888;               // region B: 14,524,416 floats
  float* COL = RA;                         // 25088*768  (pre-SAT only)
  float* QT = RA;                          // 25216*256  (SAT phase)
  float* KT = RA + 6455296;                // 25216*256
  float* VT = RB;                          // 25216*256
  float* O256 = RB + 6455296;              // 25216*256
  float* QKV = RB;                         // 25216*576  (layer loop)
  float* MLP = RA;                         // 25216*768  (layer loop)
  float* TOKRAW = Y;                       // 25088*192  (pre-assemble only)

  // --- elevation weights ---
  eleva_w_kernel<<<BATCH, 256, 0, stream>>>(xg, W_ELE);

  // --- patch embed: im2col -> NT GEMM (bias=patch_b) -> assemble(+cls,+pos) ---
  im2col_kernel<<<(MROWS_PATCH * KPATCH) / 256, 256, 0, stream>>>(x, COL);
  gemm64<1, 0><<<dim3(MROWS_PATCH / 64, DMODEL / 64), 256, 0, stream>>>(
      COL, patch_w, patch_b, nullptr, TOKRAW, MROWS_PATCH, DMODEL, KPATCH, 1.f);
  assemble_kernel<<<(BS_ROWS * DMODEL) / 256, 256, 0, stream>>>(TOKRAW, cls_tok, pos_emb, H);

  // --- SAT fusion ---
  ele_proj_kernel<<<BATCH, 256, 0, stream>>>(ele_emb, sat_wq, sat_bq, sat_wk, sat_bk,
                                             sat_wv, sat_bv, W_ELE, EQ, EK, EV);
  gemm64<0, 0><<<dim3(BS_ROWS / 64, 4), 256, 0, stream>>>(H, sat_wq, sat_bq, nullptr, QT,
                                                          BS_ROWS, 256, DMODEL, 1.f);
  gemm64<0, 0><<<dim3(BS_ROWS / 64, 4), 256, 0, stream>>>(H, sat_wk, sat_bk, nullptr, KT,
                                                          BS_ROWS, 256, DMODEL, 1.f);
  gemm64<0, 0><<<dim3(BS_ROWS / 64, 4), 256, 0, stream>>>(H, sat_wv, sat_bv, nullptr, VT,
                                                          BS_ROWS, 256, DMODEL, 1.f);
  sat_mix_kernel<<<BS_ROWS / 32, 256, 0, stream>>>(QT, KT, VT, EQ, EK, EV, O256);
  // h = (o_q0 + o_q1) @ wo + 2*bo   (linearity of the output projection)
  gemm64<0, 0><<<dim3(BS_ROWS / 64, 3), 256, 0, stream>>>(O256, sat_wo, sat_bo, nullptr, H,
                                                          BS_ROWS, DMODEL, 256, 2.f);

  // --- 12 transformer blocks ---
  for (int l = 0; l < DEPTH; l++) {
    ln_kernel<<<BS_ROWS / 4, 256, 0, stream>>>(H, ln1_g + l * DMODEL, ln1_b + l * DMODEL, Y,
                                               BS_ROWS);
    gemm64<0, 0><<<dim3(BS_ROWS / 64, 9), 256, 0, stream>>>(
        Y, qkv_w + (size_t)l * DMODEL * 576, qkv_b + l * 576, nullptr, QKV, BS_ROWS, 576,
        DMODEL, 1.f);
    attn_kernel<<<BATCH * 3, 512, 0, stream>>>(QKV, Y);
    gemm64<0, 1><<<dim3(BS_ROWS / 64, 3), 256, 0, stream>>>(
        Y, proj_w + (size_t)l * DMODEL * DMODEL, proj_b + l * DMODEL, H, H, BS_ROWS, DMODEL,
        DMODEL, 1.f);
    ln_kernel<<<BS_ROWS / 4, 256, 0, stream>>>(H, ln2_g + l * DMODEL, ln2_b + l * DMODEL, Y,
                                               BS_ROWS);
    gemm64<0, 2><<<dim3(BS_ROWS / 64, 12), 256, 0, stream>>>(
        Y, fc1_w + (size_t)l * DMODEL * MLPDIM, fc1_b + l * MLPDIM, nullptr, MLP, BS_ROWS,
        MLPDIM, DMODEL, 1.f);
    gemm64<0, 1><<<dim3(BS_ROWS / 64, 3), 256, 0, stream>>>(
        MLP, fc2_w + (size_t)l * MLPDIM * DMODEL, fc2_b + l * DMODEL, H, H, BS_ROWS, DMODEL,
        MLPDIM, 1.f);
  }

  // --- final LN on cls rows only ---
  final_ln_kernel<<<BATCH / 4, 256, 0, stream>>>(H, norm_g, norm_b, out);
}

// Round 2
// 5020.180 us; speedup vs baseline: 2.3407x; 2.3407x over previous
//
#include <hip/hip_runtime.h>

// ---------------------------------------------------------------------------
// ViT-Tiny + SAT elevation fusion. fp32 GEMMs + bf16 MFMA flash attention.
// B=128, S=197, D=192, depth=12, heads=3 (hd=64), MLP=768.
// ---------------------------------------------------------------------------

#define BATCH 128
#define SEQ 197
#define BS_ROWS (BATCH * SEQ)          // 25216
#define DMODEL 192
#define NPATCH 196
#define MROWS_PATCH (BATCH * NPATCH)   // 25088
#define KPATCH 768
#define MLPDIM 768
#define DEPTH 12
#define SPAD 224                       // padded key count for PV (7 chunks of 32)

typedef float f32x4 __attribute__((ext_vector_type(4)));
typedef short s16x8 __attribute__((ext_vector_type(8)));

__device__ __forceinline__ float wredSum(float v) {
#pragma unroll
  for (int o = 32; o > 0; o >>= 1) v += __shfl_xor(v, o, 64);
  return v;
}

__device__ __forceinline__ unsigned short f2bf(float f) {
  union { float f; unsigned u; } v;
  v.f = f;
  unsigned r = v.u + 0x7FFFu + ((v.u >> 16) & 1u);  // RNE (finite inputs)
  return (unsigned short)(r >> 16);
}

// ---------------------------------------------------------------------------
// Elevation weight: mean over x_g_norm[b] (3136 elems) -> bisect+interp -> w[b]
// ---------------------------------------------------------------------------
__global__ __launch_bounds__(256) void eleva_w_kernel(const float* __restrict__ xg,
                                                      float* __restrict__ wout) {
  const int b = blockIdx.x;
  const float* p = xg + (size_t)b * 3136;
  float s = 0.f;
  for (int i = threadIdx.x; i < 3136; i += 256) s += p[i];
  __shared__ float partial[4];
  s = wredSum(s);
  if ((threadIdx.x & 63) == 0) partial[threadIdx.x >> 6] = s;
  __syncthreads();
  if (threadIdx.x == 0) {
    float m = (partial[0] + partial[1] + partial[2] + partial[3]) / 3136.f;
    int idx = 0;
#pragma unroll
    for (int i = 0; i < 10; i++) {
      float pv = 0.1f * (float)(i + 1);
      if (pv < m) idx = i + 1;
    }
    if (idx > 9) idx = 9;
    float wv;
    if (idx == 9) {
      wv = 9.f;
    } else {
      float hi = 0.1f * (float)(idx + 1);
      float lo = (idx == 0) ? 0.f : 0.1f * (float)idx;
      wv = (float)idx - (hi - m) / (hi - lo);
    }
    wout[b] = wv / 10.f;
  }
}

// ---------------------------------------------------------------------------
// im2col for the patch conv
// ---------------------------------------------------------------------------
__global__ __launch_bounds__(256) void im2col_kernel(const float* __restrict__ x,
                                                     float* __restrict__ col) {
  const int i = blockIdx.x * 256 + threadIdx.x;
  if (i >= MROWS_PATCH * KPATCH) return;
  const int k = i % KPATCH, row = i / KPATCH;
  const int b = row / NPATCH, p = row % NPATCH;
  const int py = p / 14, px = p % 14;
  const int c = k >> 8, r = (k >> 4) & 15, cc = k & 15;
  col[i] = x[(((size_t)b * 3 + c) * 224 + (py * 16 + r)) * 224 + (px * 16 + cc)];
}

__global__ __launch_bounds__(256) void assemble_kernel(const float* __restrict__ tok_raw,
                                                       const float* __restrict__ cls,
                                                       const float* __restrict__ pos,
                                                       float* __restrict__ H) {
  const int i = blockIdx.x * 256 + threadIdx.x;
  if (i >= BS_ROWS * DMODEL) return;
  const int d = i % DMODEL, row = i / DMODEL;
  const int b = row / SEQ, s = row % SEQ;
  float v;
  if (s == 0)
    v = cls[d] + pos[d];
  else
    v = tok_raw[(size_t)(b * NPATCH + s - 1) * DMODEL + d] + pos[(size_t)s * DMODEL + d];
  H[i] = v;
}

// ---------------------------------------------------------------------------
// SAT helpers (unchanged from R1)
// ---------------------------------------------------------------------------
__global__ __launch_bounds__(256) void ele_proj_kernel(
    const float* __restrict__ ele_emb, const float* __restrict__ wq, const float* __restrict__ bq,
    const float* __restrict__ wk, const float* __restrict__ bk,
    const float* __restrict__ wv, const float* __restrict__ bv,
    const float* __restrict__ wvec, float* __restrict__ eq, float* __restrict__ ek,
    float* __restrict__ ev) {
  const int b = blockIdx.x, t = threadIdx.x;
  __shared__ float es[DMODEL];
  if (t < DMODEL) es[t] = ele_emb[t] * wvec[b];
  __syncthreads();
  float aq = bq[t], ak = bk[t], av = bv[t];
  for (int d = 0; d < DMODEL; d++) {
    const float e = es[d];
    aq += e * wq[d * 256 + t];
    ak += e * wk[d * 256 + t];
    av += e * wv[d * 256 + t];
  }
  eq[b * 256 + t] = aq;
  ek[b * 256 + t] = ak;
  ev[b * 256 + t] = av;
}

__global__ __launch_bounds__(256) void sat_mix_kernel(
    const float* __restrict__ qt, const float* __restrict__ kt, const float* __restrict__ vt,
    const float* __restrict__ eq, const float* __restrict__ ek, const float* __restrict__ ev,
    float* __restrict__ o256) {
  const int gid = blockIdx.x * 256 + threadIdx.x;
  const int tok = gid >> 3, h = gid & 7;
  if (tok >= BS_ROWS) return;
  const int b = tok / SEQ;
  const float* qp = qt + (size_t)tok * 256 + h * 32;
  const float* kp = kt + (size_t)tok * 256 + h * 32;
  const float* vp = vt + (size_t)tok * 256 + h * 32;
  const float* eqp = eq + b * 256 + h * 32;
  const float* ekp = ek + b * 256 + h * 32;
  const float* evp = ev + b * 256 + h * 32;
  float s00 = 0.f, s01 = 0.f, s10 = 0.f, s11 = 0.f;
#pragma unroll 8
  for (int d = 0; d < 32; d++) {
    const float q_ = qp[d], k_ = kp[d], eq_ = eqp[d], ek_ = ekp[d];
    s00 += q_ * k_;
    s01 += q_ * ek_;
    s10 += eq_ * k_;
    s11 += eq_ * ek_;
  }
  const float sc = 0.17677669529663687f;
  s00 *= sc; s01 *= sc; s10 *= sc; s11 *= sc;
  const float m0 = fmaxf(s00, s01), m1 = fmaxf(s10, s11);
  const float e00 = __expf(s00 - m0), e01 = __expf(s01 - m0);
  const float e10 = __expf(s10 - m1), e11 = __expf(s11 - m1);
  const float w0 = e00 / (e00 + e01) + e10 / (e10 + e11);
  const float w1 = e01 / (e00 + e01) + e11 / (e10 + e11);
  float* op = o256 + (size_t)tok * 256 + h * 32;
#pragma unroll 8
  for (int d = 0; d < 32; d++) op[d] = w0 * vp[d] + w1 * evp[d];
}

// ---------------------------------------------------------------------------
// Generic fp32 GEMM, BM=BN=64, BK=16 (unchanged from R1)
// ---------------------------------------------------------------------------
template <int BLAYOUT, int EPI>
__global__ __launch_bounds__(256) void gemm64(const float* __restrict__ A,
                                              const float* __restrict__ B,
                                              const float* __restrict__ bias,
                                              const float* res, float* C, int M, int N,
                                              int K, float bias_scale) {
  __shared__ float As[16][68];
  __shared__ float Bs[16][68];
  const int tid = threadIdx.x;
  const int m0 = blockIdx.x * 64, n0 = blockIdx.y * 64;
  const int tx = tid & 15, ty = tid >> 4;
  const int la_r = tid >> 2, la_k = (tid & 3) << 2;
  float acc[4][4] = {{0.f}};
  for (int k0 = 0; k0 < K; k0 += 16) {
    const float4 av = *(const float4*)(A + (size_t)(m0 + la_r) * K + (k0 + la_k));
    As[la_k + 0][la_r] = av.x;
    As[la_k + 1][la_r] = av.y;
    As[la_k + 2][la_r] = av.z;
    As[la_k + 3][la_r] = av.w;
    if (BLAYOUT == 0) {
      const float4 bv = *(const float4*)(B + (size_t)(k0 + ty) * N + (n0 + tx * 4));
      *(float4*)&Bs[ty][tx * 4] = bv;
    } else {
      const float4 bv = *(const float4*)(B + (size_t)(n0 + la_r) * K + (k0 + la_k));
      Bs[la_k + 0][la_r] = bv.x;
      Bs[la_k + 1][la_r] = bv.y;
      Bs[la_k + 2][la_r] = bv.z;
      Bs[la_k + 3][la_r] = bv.w;
    }
    __syncthreads();
#pragma unroll
    for (int kk = 0; kk < 16; kk++) {
      const float4 a4 = *(const float4*)&As[kk][ty * 4];
      const float4 b4 = *(const float4*)&Bs[kk][tx * 4];
      const float a_[4] = {a4.x, a4.y, a4.z, a4.w};
      const float b_[4] = {b4.x, b4.y, b4.z, b4.w};
#pragma unroll
      for (int i = 0; i < 4; i++)
#pragma unroll
        for (int j = 0; j < 4; j++) acc[i][j] += a_[i] * b_[j];
    }
    __syncthreads();
  }
  float bvals[4];
#pragma unroll
  for (int j = 0; j < 4; j++) bvals[j] = bias[n0 + tx * 4 + j] * bias_scale;
#pragma unroll
  for (int i = 0; i < 4; i++) {
    const size_t m = m0 + ty * 4 + i;
    float v[4];
#pragma unroll
    for (int j = 0; j < 4; j++) {
      float t = acc[i][j] + bvals[j];
      if (EPI == 2) t = 0.5f * t * (1.0f + erff(t * 0.70710678118654752f));
      v[j] = t;
    }
    if (EPI == 1) {
      const float4 rv = *(const float4*)(res + m * N + n0 + tx * 4);
      v[0] += rv.x; v[1] += rv.y; v[2] += rv.z; v[3] += rv.w;
    }
    *(float4*)(C + m * N + n0 + tx * 4) = make_float4(v[0], v[1], v[2], v[3]);
  }
}

// ---------------------------------------------------------------------------
// LayerNorm (unchanged)
// ---------------------------------------------------------------------------
__global__ __launch_bounds__(256) void ln_kernel(const float* __restrict__ X,
                                                 const float* __restrict__ g,
                                                 const float* __restrict__ bta,
                                                 float* __restrict__ Y, int nrows) {
  const int w = threadIdx.x >> 6, lane = threadIdx.x & 63;
  const int row = blockIdx.x * 4 + w;
  if (row >= nrows) return;
  const float* x = X + (size_t)row * DMODEL;
  const float x0 = x[lane], x1 = x[lane + 64], x2 = x[lane + 128];
  const float m = wredSum(x0 + x1 + x2) * (1.f / 192.f);
  const float d0 = x0 - m, d1 = x1 - m, d2 = x2 - m;
  const float v = wredSum(d0 * d0 + d1 * d1 + d2 * d2) * (1.f / 192.f);
  const float inv = rsqrtf(v + 1e-5f);
  float* y = Y + (size_t)row * DMODEL;
  y[lane] = d0 * inv * g[lane] + bta[lane];
  y[lane + 64] = d1 * inv * g[lane + 64] + bta[lane + 64];
  y[lane + 128] = d2 * inv * g[lane + 128] + bta[lane + 128];
}

__global__ __launch_bounds__(256) void final_ln_kernel(const float* __restrict__ H,
                                                       const float* __restrict__ g,
                                                       const float* __restrict__ bta,
                                                       float* __restrict__ out) {
  const int w = threadIdx.x >> 6, lane = threadIdx.x & 63;
  const int bi = blockIdx.x * 4 + w;
  if (bi >= BATCH) return;
  const float* x = H + (size_t)bi * SEQ * DMODEL;
  const float x0 = x[lane], x1 = x[lane + 64], x2 = x[lane + 128];
  const float m = wredSum(x0 + x1 + x2) * (1.f / 192.f);
  const float d0 = x0 - m, d1 = x1 - m, d2 = x2 - m;
  const float v = wredSum(d0 * d0 + d1 * d1 + d2 * d2) * (1.f / 192.f);
  const float inv = rsqrtf(v + 1e-5f);
  float* y = out + (size_t)bi * DMODEL;
  y[lane] = d0 * inv * g[lane] + bta[lane];
  y[lane + 64] = d1 * inv * g[lane + 64] + bta[lane + 64];
  y[lane + 128] = d2 * inv * g[lane + 128] + bta[lane + 128];
}

// ---------------------------------------------------------------------------
// V^T conversion: QKV fp32 -> Vt bf16 [b][h][64][SPAD], zero-padded keys.
// LDS transpose so both global read and write are coalesced.
// ---------------------------------------------------------------------------
__global__ __launch_bounds__(256) void vtrans_kernel(const float* __restrict__ qkv,
                                                     unsigned short* __restrict__ vt) {
  const int bid = blockIdx.x;
  const int sc = bid & 3, bh = bid >> 2;
  const int b = bh / 3, h = bh % 3;
  const int s0 = sc * 64;
  __shared__ float t[64][65];
  const int tid = threadIdx.x;
  for (int e = tid; e < 64 * 64; e += 256) {
    const int sp = e >> 6, d = e & 63;
    const int s = s0 + sp;
    t[sp][d] = (s < SEQ) ? qkv[((size_t)(b * SEQ + s)) * 576 + 384 + h * 64 + d] : 0.f;
  }
  __syncthreads();
  for (int e = tid; e < 64 * 64; e += 256) {
    const int d = e >> 6, sp = e & 63;
    const int s = s0 + sp;
    if (s < SPAD) vt[((size_t)bh * 64 + d) * SPAD + s] = f2bf(t[sp][d]);
  }
}

// ---------------------------------------------------------------------------
// bf16 MFMA flash attention. One 64-thread wave per (b, h, 16-q-row tile).
// Q/K fragments read directly from fp32 QKV (L2-resident), converted in-reg.
// Scores: 13 k-tiles x 2 mfma_f32_16x16x32_bf16. Softmax in-register
// (C layout: col=lane&15, row=(lane>>4)*4+reg). P -> LDS bf16 [16][232]
// (stride 232: 16B-slot index 29 = 5 mod 8 -> conflict-free b128 reads).
// PV: 7 chunks x 4 d-tiles vs global Vt bf16.
// ---------------------------------------------------------------------------
__global__ __launch_bounds__(64) void attn_mfma_kernel(const float* __restrict__ qkv,
                                                       const unsigned short* __restrict__ vt,
                                                       float* __restrict__ out) {
  const int bid = blockIdx.x;
  const int bh = bid / 13, qt = bid % 13;
  const int b = bh / 3, h = bh % 3;
  const int row0 = b * SEQ;
  const int q0 = qt * 16;
  const int lane = threadIdx.x;
  const int c = lane & 15, g = lane >> 4;

  __shared__ __attribute__((aligned(16))) unsigned short P[16][232];

  // --- Q fragments (row = q0+c, k = g*8+i), clamped to valid rows ---
  const int qr = row0 + min(q0 + c, SEQ - 1);
  const float* qp = qkv + (size_t)qr * 576 + h * 64 + g * 8;
  s16x8 qlo, qhi;
  {
    const float4 a0 = *(const float4*)(qp);
    const float4 a1 = *(const float4*)(qp + 4);
    const float4 b0 = *(const float4*)(qp + 32);
    const float4 b1 = *(const float4*)(qp + 36);
    qlo[0] = (short)f2bf(a0.x); qlo[1] = (short)f2bf(a0.y);
    qlo[2] = (short)f2bf(a0.z); qlo[3] = (short)f2bf(a0.w);
    qlo[4] = (short)f2bf(a1.x); qlo[5] = (short)f2bf(a1.y);
    qlo[6] = (short)f2bf(a1.z); qlo[7] = (short)f2bf(a1.w);
    qhi[0] = (short)f2bf(b0.x); qhi[1] = (short)f2bf(b0.y);
    qhi[2] = (short)f2bf(b0.z); qhi[3] = (short)f2bf(b0.w);
    qhi[4] = (short)f2bf(b1.x); qhi[5] = (short)f2bf(b1.y);
    qhi[6] = (short)f2bf(b1.z); qhi[7] = (short)f2bf(b1.w);
  }

  // --- scores: 13 key-tiles of 16 ---
  f32x4 acc[13];
#pragma unroll
  for (int t = 0; t < 13; t++) {
    const int kr = row0 + min(t * 16 + c, SEQ - 1);
    const float* kp = qkv + (size_t)kr * 576 + 192 + h * 64 + g * 8;
    const float4 a0 = *(const float4*)(kp);
    const float4 a1 = *(const float4*)(kp + 4);
    const float4 b0 = *(const float4*)(kp + 32);
    const float4 b1 = *(const float4*)(kp + 36);
    s16x8 klo, khi;
    klo[0] = (short)f2bf(a0.x); klo[1] = (short)f2bf(a0.y);
    klo[2] = (short)f2bf(a0.z); klo[3] = (short)f2bf(a0.w);
    klo[4] = (short)f2bf(a1.x); klo[5] = (short)f2bf(a1.y);
    klo[6] = (short)f2bf(a1.z); klo[7] = (short)f2bf(a1.w);
    khi[0] = (short)f2bf(b0.x); khi[1] = (short)f2bf(b0.y);
    khi[2] = (short)f2bf(b0.z); khi[3] = (short)f2bf(b0.w);
    khi[4] = (short)f2bf(b1.x); khi[5] = (short)f2bf(b1.y);
    khi[6] = (short)f2bf(b1.z); khi[7] = (short)f2bf(b1.w);
    f32x4 z = {0.f, 0.f, 0.f, 0.f};
    z = __builtin_amdgcn_mfma_f32_16x16x32_bf16(qlo, klo, z, 0, 0, 0);
    acc[t] = __builtin_amdgcn_mfma_f32_16x16x32_bf16(qhi, khi, z, 0, 0, 0);
  }

  // --- softmax per row (row = g*4+r, cols on 16 lanes of this g-group) ---
  const bool m12 = (c >= 5);  // tile 12 cols 192+c >= 197 invalid
#pragma unroll
  for (int r = 0; r < 4; r++) {
    float mx = -INFINITY;
#pragma unroll
    for (int t = 0; t < 13; t++) {
      const float v = (t == 12 && m12) ? -INFINITY : acc[t][r];
      mx = fmaxf(mx, v);
    }
#pragma unroll
    for (int o = 1; o <= 8; o <<= 1) mx = fmaxf(mx, __shfl_xor(mx, o, 64));
    const float ms = mx * 0.125f;
    float sum = 0.f;
#pragma unroll
    for (int t = 0; t < 13; t++) {
      const float e = (t == 12 && m12) ? 0.f : __expf(acc[t][r] * 0.125f - ms);
      acc[t][r] = e;
      sum += e;
    }
#pragma unroll
    for (int o = 1; o <= 8; o <<= 1) sum += __shfl_xor(sum, o, 64);
    const float inv = 1.f / sum;
#pragma unroll
    for (int t = 0; t < 13; t++) P[g * 4 + r][t * 16 + c] = f2bf(acc[t][r] * inv);
  }
  // zero pad columns 208..223 (rows: c, cols 208+g*4..+3)
  {
    unsigned short z4[4] = {0, 0, 0, 0};
    *(uint2*)&P[c][208 + g * 4] = *(uint2*)z4;
  }
  __builtin_amdgcn_s_waitcnt(0);  // ensure LDS writes land (same wave reads next)

  // --- PV: O[16][64] = P[16][224] @ V[224][64] ---
  f32x4 oacc[4];
#pragma unroll
  for (int dt = 0; dt < 4; dt++) oacc[dt] = (f32x4){0.f, 0.f, 0.f, 0.f};
  const unsigned short* vbase = vt + (size_t)bh * 64 * SPAD;
#pragma unroll
  for (int ch = 0; ch < 7; ch++) {
    const s16x8 pa = *(const s16x8*)&P[c][ch * 32 + g * 8];
#pragma unroll
    for (int dt = 0; dt < 4; dt++) {
      const s16x8 vb = *(const s16x8*)(vbase + (size_t)(dt * 16 + c) * SPAD + ch * 32 + g * 8);
      oacc[dt] = __builtin_amdgcn_mfma_f32_16x16x32_bf16(pa, vb, oacc[dt], 0, 0, 0);
    }
  }

  // --- write O (row = g*4+r, col = dt*16+c), mask pad q rows ---
#pragma unroll
  for (int dt = 0; dt < 4; dt++) {
#pragma unroll
    for (int r = 0; r < 4; r++) {
      const int q = q0 + g * 4 + r;
      if (q < SEQ) out[(size_t)(row0 + q) * DMODEL + h * 64 + dt * 16 + c] = oacc[dt][r];
    }
  }
}

// ---------------------------------------------------------------------------
extern "C" void kernel_launch(void* const* d_in, const int* in_sizes, int n_in,
                              void* d_out, int out_size, void* d_ws, size_t ws_size,
                              hipStream_t stream) {
  const float* x       = (const float*)d_in[0];
  const float* xg      = (const float*)d_in[1];
  const float* patch_w = (const float*)d_in[2];
  const float* patch_b = (const float*)d_in[3];
  const float* cls_tok = (const float*)d_in[4];
  const float* pos_emb = (const float*)d_in[5];
  const float* ele_emb = (const float*)d_in[6];
  const float* sat_wq  = (const float*)d_in[7];
  const float* sat_bq  = (const float*)d_in[8];
  const float* sat_wk  = (const float*)d_in[9];
  const float* sat_bk  = (const float*)d_in[10];
  const float* sat_wv  = (const float*)d_in[11];
  const float* sat_bv  = (const float*)d_in[12];
  const float* sat_wo  = (const float*)d_in[13];
  const float* sat_bo  = (const float*)d_in[14];
  const float* ln1_g   = (const float*)d_in[15];
  const float* ln1_b   = (const float*)d_in[16];
  const float* qkv_w   = (const float*)d_in[17];
  const float* qkv_b   = (const float*)d_in[18];
  const float* proj_w  = (const float*)d_in[19];
  const float* proj_b  = (const float*)d_in[20];
  const float* ln2_g   = (const float*)d_in[21];
  const float* ln2_b   = (const float*)d_in[22];
  const float* fc1_w   = (const float*)d_in[23];
  const float* fc1_b   = (const float*)d_in[24];
  const float* fc2_w   = (const float*)d_in[25];
  const float* fc2_b   = (const float*)d_in[26];
  const float* norm_g  = (const float*)d_in[27];
  const float* norm_b  = (const float*)d_in[28];
  float* out = (float*)d_out;
  float* ws = (float*)d_ws;

  // Workspace layout (floats). Total = 43,671,808 floats ~= 167 MiB.
  float* W_ELE = ws;                       // 128
  float* EQ = ws + 256;                    // 3 x 32768
  float* EK = EQ + 32768;
  float* EV = EK + 32768;
  float* H = ws + 98560;                   // 25216*192
  float* Y = H + 4841472;                  // 25216*192
  float* RA = Y + 4841472;                 // region A: 19,365,888 floats
  float* RB = RA + 19365888;               // region B: 14,524,416 floats
  float* COL = RA;                         // 25088*768  (pre-SAT only)
  float* QT = RA;                          // 25216*256  (SAT phase)
  float* KT = RA + 6455296;                // 25216*256
  float* VT = RB;                          // 25216*256
  float* O256 = RB + 6455296;              // 25216*256
  float* QKV = RB;                         // 25216*576  (layer loop)
  float* MLP = RA;                         // 25216*768  (layer loop)
  unsigned short* VTB = (unsigned short*)RA;  // bf16 V^T [128][3][64][224] (attn phase)
  float* TOKRAW = Y;                       // 25088*192  (pre-assemble only)

  eleva_w_kernel<<<BATCH, 256, 0, stream>>>(xg, W_ELE);

  im2col_kernel<<<(MROWS_PATCH * KPATCH) / 256, 256, 0, stream>>>(x, COL);
  gemm64<1, 0><<<dim3(MROWS_PATCH / 64, DMODEL / 64), 256, 0, stream>>>(
      COL, patch_w, patch_b, nullptr, TOKRAW, MROWS_PATCH, DMODEL, KPATCH, 1.f);
  assemble_kernel<<<(BS_ROWS * DMODEL) / 256, 256, 0, stream>>>(TOKRAW, cls_tok, pos_emb, H);

  ele_proj_kernel<<<BATCH, 256, 0, stream>>>(ele_emb, sat_wq, sat_bq, sat_wk, sat_bk,
                                             sat_wv, sat_bv, W_ELE, EQ, EK, EV);
  gemm64<0, 0><<<dim3(BS_ROWS / 64, 4), 256, 0, stream>>>(H, sat_wq, sat_bq, nullptr, QT,
                                                          BS_ROWS, 256, DMODEL, 1.f);
  gemm64<0, 0><<<dim3(BS_ROWS / 64, 4), 256, 0, stream>>>(H, sat_wk, sat_bk, nullptr, KT,
                                                          BS_ROWS, 256, DMODEL, 1.f);
  gemm64<0, 0><<<dim3(BS_ROWS / 64, 4), 256, 0, stream>>>(H, sat_wv, sat_bv, nullptr, VT,
                                                          BS_ROWS, 256, DMODEL, 1.f);
  sat_mix_kernel<<<BS_ROWS / 32, 256, 0, stream>>>(QT, KT, VT, EQ, EK, EV, O256);
  gemm64<0, 0><<<dim3(BS_ROWS / 64, 3), 256, 0, stream>>>(O256, sat_wo, sat_bo, nullptr, H,
                                                          BS_ROWS, DMODEL, 256, 2.f);

  for (int l = 0; l < DEPTH; l++) {
    ln_kernel<<<BS_ROWS / 4, 256, 0, stream>>>(H, ln1_g + l * DMODEL, ln1_b + l * DMODEL, Y,
                                               BS_ROWS);
    gemm64<0, 0><<<dim3(BS_ROWS / 64, 9), 256, 0, stream>>>(
        Y, qkv_w + (size_t)l * DMODEL * 576, qkv_b + l * 576, nullptr, QKV, BS_ROWS, 576,
        DMODEL, 1.f);
    vtrans_kernel<<<BATCH * 3 * 4, 256, 0, stream>>>(QKV, VTB);
    attn_mfma_kernel<<<BATCH * 3 * 13, 64, 0, stream>>>(QKV, VTB, Y);
    gemm64<0, 1><<<dim3(BS_ROWS / 64, 3), 256, 0, stream>>>(
        Y, proj_w + (size_t)l * DMODEL * DMODEL, proj_b + l * DMODEL, H, H, BS_ROWS, DMODEL,
        DMODEL, 1.f);
    ln_kernel<<<BS_ROWS / 4, 256, 0, stream>>>(H, ln2_g + l * DMODEL, ln2_b + l * DMODEL, Y,
                                               BS_ROWS);
    gemm64<0, 2><<<dim3(BS_ROWS / 64, 12), 256, 0, stream>>>(
        Y, fc1_w + (size_t)l * DMODEL * MLPDIM, fc1_b + l * MLPDIM, nullptr, MLP, BS_ROWS,
        MLPDIM, DMODEL, 1.f);
    gemm64<0, 1><<<dim3(BS_ROWS / 64, 3), 256, 0, stream>>>(
        MLP, fc2_w + (size_t)l * MLPDIM * DMODEL, fc2_b + l * DMODEL, H, H, BS_ROWS, DMODEL,
        MLPDIM, 1.f);
  }

  final_ln_kernel<<<BATCH / 4, 256, 0, stream>>>(H, norm_g, norm_b, out);
}

// Round 3
// 2011.481 us; speedup vs baseline: 5.8419x; 2.4958x over previous
//
#include <hip/hip_runtime.h>

// ---------------------------------------------------------------------------
// ViT-Tiny + SAT elevation fusion. bf16 MFMA GEMMs + bf16 MFMA flash attn.
// B=128, S=197, D=192, depth=12, heads=3 (hd=64), MLP=768.
// Residual stream H kept fp32; all GEMM inputs bf16; accum fp32 in AGPRs.
// ---------------------------------------------------------------------------

#define BATCH 128
#define SEQ 197
#define BS_ROWS (BATCH * SEQ)          // 25216 = 197*128
#define DMODEL 192
#define NPATCH 196
#define MROWS_PATCH (BATCH * NPATCH)   // 25088 = 196*128
#define KPATCH 768
#define MLPDIM 768
#define DEPTH 12
#define SPAD 224

typedef float f32x4 __attribute__((ext_vector_type(4)));
typedef short s16x8 __attribute__((ext_vector_type(8)));

__device__ __forceinline__ float wredSum(float v) {
#pragma unroll
  for (int o = 32; o > 0; o >>= 1) v += __shfl_xor(v, o, 64);
  return v;
}

__device__ __forceinline__ unsigned short f2bf(float f) {
  union { float f; unsigned u; } v;
  v.f = f;
  unsigned r = v.u + 0x7FFFu + ((v.u >> 16) & 1u);  // RNE
  return (unsigned short)(r >> 16);
}
__device__ __forceinline__ float bf2f(unsigned short u) {
  union { unsigned u; float f; } v;
  v.u = ((unsigned)u) << 16;
  return v.f;
}

// ---------------------------------------------------------------------------
// Elevation weight
// ---------------------------------------------------------------------------
__global__ __launch_bounds__(256) void eleva_w_kernel(const float* __restrict__ xg,
                                                      float* __restrict__ wout) {
  const int b = blockIdx.x;
  const float* p = xg + (size_t)b * 3136;
  float s = 0.f;
  for (int i = threadIdx.x; i < 3136; i += 256) s += p[i];
  __shared__ float partial[4];
  s = wredSum(s);
  if ((threadIdx.x & 63) == 0) partial[threadIdx.x >> 6] = s;
  __syncthreads();
  if (threadIdx.x == 0) {
    float m = (partial[0] + partial[1] + partial[2] + partial[3]) / 3136.f;
    int idx = 0;
#pragma unroll
    for (int i = 0; i < 10; i++) {
      float pv = 0.1f * (float)(i + 1);
      if (pv < m) idx = i + 1;
    }
    if (idx > 9) idx = 9;
    float wv;
    if (idx == 9) {
      wv = 9.f;
    } else {
      float hi = 0.1f * (float)(idx + 1);
      float lo = (idx == 0) ? 0.f : 0.1f * (float)idx;
      wv = (float)idx - (hi - m) / (hi - lo);
    }
    wout[b] = wv / 10.f;
  }
}

// ---------------------------------------------------------------------------
// Weight transpose fp32 [R][C] -> bf16 [C][R], per-layer via blockIdx.z
// ---------------------------------------------------------------------------
__global__ __launch_bounds__(256) void wtrans_kernel(const float* __restrict__ in,
                                                     unsigned short* __restrict__ out,
                                                     int R, int C) {
  const int z = blockIdx.z;
  in += (size_t)z * R * C;
  out += (size_t)z * R * C;
  const int c0 = blockIdx.x * 32, r0 = blockIdx.y * 32;
  __shared__ float t[32][33];
  const int tr = threadIdx.x >> 3, tc = (threadIdx.x & 7) * 4;
  const float4 v = *(const float4*)(in + (size_t)(r0 + tr) * C + c0 + tc);
  t[tr][tc] = v.x; t[tr][tc + 1] = v.y; t[tr][tc + 2] = v.z; t[tr][tc + 3] = v.w;
  __syncthreads();
  ushort4 o;
  o.x = f2bf(t[tc + 0][tr]);
  o.y = f2bf(t[tc + 1][tr]);
  o.z = f2bf(t[tc + 2][tr]);
  o.w = f2bf(t[tc + 3][tr]);
  *(ushort4*)(out + (size_t)(c0 + tr) * R + r0 + tc) = o;
}

// fp32 -> bf16 flat convert (patch_w is already [N][K])
__global__ __launch_bounds__(256) void convert_kernel(const float* __restrict__ in,
                                                      unsigned short* __restrict__ out, int n4) {
  const int i = blockIdx.x * 256 + threadIdx.x;
  if (i >= n4) return;
  const float4 v = *(const float4*)(in + (size_t)i * 4);
  ushort4 o;
  o.x = f2bf(v.x); o.y = f2bf(v.y); o.z = f2bf(v.z); o.w = f2bf(v.w);
  *(ushort4*)(out + (size_t)i * 4) = o;
}

// ---------------------------------------------------------------------------
// im2col (bf16 out)
// ---------------------------------------------------------------------------
__global__ __launch_bounds__(256) void im2col_kernel(const float* __restrict__ x,
                                                     unsigned short* __restrict__ col) {
  const int i = blockIdx.x * 256 + threadIdx.x;
  if (i >= MROWS_PATCH * KPATCH) return;
  const int k = i % KPATCH, row = i / KPATCH;
  const int b = row / NPATCH, p = row % NPATCH;
  const int py = p / 14, px = p % 14;
  const int c = k >> 8, r = (k >> 4) & 15, cc = k & 15;
  col[i] = f2bf(x[(((size_t)b * 3 + c) * 224 + (py * 16 + r)) * 224 + (px * 16 + cc)]);
}

// tok_raw bf16 + cls/pos fp32 -> H fp32 AND Hbf bf16
__global__ __launch_bounds__(256) void assemble_kernel(const unsigned short* __restrict__ tok_raw,
                                                       const float* __restrict__ cls,
                                                       const float* __restrict__ pos,
                                                       float* __restrict__ H,
                                                       unsigned short* __restrict__ Hbf) {
  const int i = blockIdx.x * 256 + threadIdx.x;
  if (i >= BS_ROWS * DMODEL) return;
  const int d = i % DMODEL, row = i / DMODEL;
  const int b = row / SEQ, s = row % SEQ;
  float v;
  if (s == 0)
    v = cls[d] + pos[d];
  else
    v = bf2f(tok_raw[(size_t)(b * NPATCH + s - 1) * DMODEL + d]) + pos[(size_t)s * DMODEL + d];
  H[i] = v;
  Hbf[i] = f2bf(v);
}

// ---------------------------------------------------------------------------
// SAT helpers
// ---------------------------------------------------------------------------
__global__ __launch_bounds__(256) void ele_proj_kernel(
    const float* __restrict__ ele_emb, const float* __restrict__ wq, const float* __restrict__ bq,
    const float* __restrict__ wk, const float* __restrict__ bk,
    const float* __restrict__ wv, const float* __restrict__ bv,
    const float* __restrict__ wvec, float* __restrict__ eq, float* __restrict__ ek,
    float* __restrict__ ev) {
  const int b = blockIdx.x, t = threadIdx.x;
  __shared__ float es[DMODEL];
  if (t < DMODEL) es[t] = ele_emb[t] * wvec[b];
  __syncthreads();
  float aq = bq[t], ak = bk[t], av = bv[t];
  for (int d = 0; d < DMODEL; d++) {
    const float e = es[d];
    aq += e * wq[d * 256 + t];
    ak += e * wk[d * 256 + t];
    av += e * wv[d * 256 + t];
  }
  eq[b * 256 + t] = aq;
  ek[b * 256 + t] = ak;
  ev[b * 256 + t] = av;
}

__global__ __launch_bounds__(256) void sat_mix_kernel(
    const unsigned short* __restrict__ qt, const unsigned short* __restrict__ kt,
    const unsigned short* __restrict__ vt, const float* __restrict__ eq,
    const float* __restrict__ ek, const float* __restrict__ ev,
    unsigned short* __restrict__ o256) {
  const int gid = blockIdx.x * 256 + threadIdx.x;
  const int tok = gid >> 3, h = gid & 7;
  if (tok >= BS_ROWS) return;
  const int b = tok / SEQ;
  const unsigned short* qp = qt + (size_t)tok * 256 + h * 32;
  const unsigned short* kp = kt + (size_t)tok * 256 + h * 32;
  const unsigned short* vp = vt + (size_t)tok * 256 + h * 32;
  const float* eqp = eq + b * 256 + h * 32;
  const float* ekp = ek + b * 256 + h * 32;
  const float* evp = ev + b * 256 + h * 32;
  float s00 = 0.f, s01 = 0.f, s10 = 0.f, s11 = 0.f;
#pragma unroll 8
  for (int d = 0; d < 32; d++) {
    const float q_ = bf2f(qp[d]), k_ = bf2f(kp[d]), eq_ = eqp[d], ek_ = ekp[d];
    s00 += q_ * k_;
    s01 += q_ * ek_;
    s10 += eq_ * k_;
    s11 += eq_ * ek_;
  }
  const float sc = 0.17677669529663687f;
  s00 *= sc; s01 *= sc; s10 *= sc; s11 *= sc;
  const float m0 = fmaxf(s00, s01), m1 = fmaxf(s10, s11);
  const float e00 = __expf(s00 - m0), e01 = __expf(s01 - m0);
  const float e10 = __expf(s10 - m1), e11 = __expf(s11 - m1);
  const float w0 = e00 / (e00 + e01) + e10 / (e10 + e11);
  const float w1 = e01 / (e00 + e01) + e11 / (e10 + e11);
  unsigned short* op = o256 + (size_t)tok * 256 + h * 32;
#pragma unroll 8
  for (int d = 0; d < 32; d++) op[d] = f2bf(w0 * bf2f(vp[d]) + w1 * evp[d]);
}

// ---------------------------------------------------------------------------
// bf16 MFMA GEMM. BM=128, BN=64, BK template (192/128), 256 thr (4 waves 2x2),
// wave tile 64x32 = 4x2 frags of 16x16x32. A [M][K] bf16, Bt [N][K] bf16.
// LDS staged via global_load_lds width=16 with XOR slot swizzle
// (col16 ^= row&7): linear LDS dest + inverse-swizzled global source,
// forward-swizzled ds_read (rule #21) -> conflict-free b128 frag reads.
// EPI: 0 bias->bf16; 1 bias+gelu->bf16; 2 bias+res(f32)->f32; 3 2*bias->f32.
// Requires M%128==0, N%64==0, K%BK==0.
// ---------------------------------------------------------------------------
template <int BK, int EPI>
__global__ __launch_bounds__(256) void gemm_mfma(const unsigned short* __restrict__ A,
                                                 const unsigned short* __restrict__ Bt,
                                                 const float* __restrict__ bias,
                                                 const float* __restrict__ res,
                                                 void* __restrict__ Cout, int M, int N, int K) {
  constexpr int SLOTS = BK / 8;  // 16B slots per row
  __shared__ unsigned short As[128 * BK];
  __shared__ unsigned short Bs[64 * BK];
  const int tid = threadIdx.x, lane = tid & 63, w = tid >> 6;
  const int n0 = blockIdx.x * 64;
  const int m0 = blockIdx.y * 128;
  const int c = lane & 15, g = lane >> 4;
  const int wm = (w >> 1) * 64, wn = (w & 1) * 32;
  f32x4 acc[4][2] = {};
  for (int k0 = 0; k0 < K; k0 += BK) {
    if (k0) __syncthreads();
    // --- stage A: wave w covers rows [w*32, w*32+32) ---
    constexpr int AI = 32 * SLOTS / 64;
#pragma unroll
    for (int it = 0; it < AI; it++) {
      const int s = it * 64 + lane;
      const int r = w * 32 + s / SLOTS;
      const int col = s % SLOTS;
      const int scol = col ^ (r & 7);
      const unsigned short* gp = A + (size_t)(m0 + r) * K + k0 + scol * 8;
      __builtin_amdgcn_global_load_lds(
          (const __attribute__((address_space(1))) unsigned int*)gp,
          (__attribute__((address_space(3))) unsigned int*)(As + ((size_t)(w * 32) * SLOTS + it * 64) * 8),
          16, 0, 0);
    }
    // --- stage B: wave w covers rows [w*16, w*16+16) ---
    constexpr int BI = 16 * SLOTS / 64;
#pragma unroll
    for (int it = 0; it < BI; it++) {
      const int s = it * 64 + lane;
      const int r = w * 16 + s / SLOTS;
      const int col = s % SLOTS;
      const int scol = col ^ (r & 7);
      const unsigned short* gp = Bt + (size_t)(n0 + r) * K + k0 + scol * 8;
      __builtin_amdgcn_global_load_lds(
          (const __attribute__((address_space(1))) unsigned int*)gp,
          (__attribute__((address_space(3))) unsigned int*)(Bs + ((size_t)(w * 16) * SLOTS + it * 64) * 8),
          16, 0, 0);
    }
    __syncthreads();
    // --- compute ---
#pragma unroll
    for (int kk = 0; kk < BK / 32; kk++) {
      const int sw = ((kk * 4 + g) ^ (c & 7)) << 3;
      s16x8 af[4], bfr[2];
#pragma unroll
      for (int i = 0; i < 4; i++) af[i] = *(const s16x8*)&As[(wm + i * 16 + c) * BK + sw];
#pragma unroll
      for (int j = 0; j < 2; j++) bfr[j] = *(const s16x8*)&Bs[(wn + j * 16 + c) * BK + sw];
#pragma unroll
      for (int i = 0; i < 4; i++)
#pragma unroll
        for (int j = 0; j < 2; j++)
          acc[i][j] = __builtin_amdgcn_mfma_f32_16x16x32_bf16(af[i], bfr[j], acc[i][j], 0, 0, 0);
    }
  }
  // --- epilogue: C row = m0+wm+i*16+g*4+r_, col = n0+wn+j*16+c ---
  const int ncol0 = n0 + wn + c;
  float b0 = bias[ncol0], b1 = bias[ncol0 + 16];
  if (EPI == 3) { b0 *= 2.f; b1 *= 2.f; }
#pragma unroll
  for (int i = 0; i < 4; i++) {
#pragma unroll
    for (int r_ = 0; r_ < 4; r_++) {
      const size_t m = m0 + wm + i * 16 + g * 4 + r_;
#pragma unroll
      for (int j = 0; j < 2; j++) {
        float v = acc[i][j][r_] + (j ? b1 : b0);
        const size_t idx = m * N + ncol0 + j * 16;
        if (EPI == 0) {
          ((unsigned short*)Cout)[idx] = f2bf(v);
        } else if (EPI == 1) {
          v = 0.5f * v * (1.0f + erff(v * 0.70710678118654752f));
          ((unsigned short*)Cout)[idx] = f2bf(v);
        } else if (EPI == 2) {
          ((float*)Cout)[idx] = v + res[idx];
        } else {
          ((float*)Cout)[idx] = v;
        }
      }
    }
  }
}

// ---------------------------------------------------------------------------
// LayerNorm: fp32 in -> bf16 out
// ---------------------------------------------------------------------------
__global__ __launch_bounds__(256) void ln_kernel(const float* __restrict__ X,
                                                 const float* __restrict__ g,
                                                 const float* __restrict__ bta,
                                                 unsigned short* __restrict__ Y, int nrows) {
  const int w = threadIdx.x >> 6, lane = threadIdx.x & 63;
  const int row = blockIdx.x * 4 + w;
  if (row >= nrows) return;
  const float* x = X + (size_t)row * DMODEL;
  const float x0 = x[lane], x1 = x[lane + 64], x2 = x[lane + 128];
  const float m = wredSum(x0 + x1 + x2) * (1.f / 192.f);
  const float d0 = x0 - m, d1 = x1 - m, d2 = x2 - m;
  const float v = wredSum(d0 * d0 + d1 * d1 + d2 * d2) * (1.f / 192.f);
  const float inv = rsqrtf(v + 1e-5f);
  unsigned short* y = Y + (size_t)row * DMODEL;
  y[lane] = f2bf(d0 * inv * g[lane] + bta[lane]);
  y[lane + 64] = f2bf(d1 * inv * g[lane + 64] + bta[lane + 64]);
  y[lane + 128] = f2bf(d2 * inv * g[lane + 128] + bta[lane + 128]);
}

__global__ __launch_bounds__(256) void final_ln_kernel(const float* __restrict__ H,
                                                       const float* __restrict__ g,
                                                       const float* __restrict__ bta,
                                                       float* __restrict__ out) {
  const int w = threadIdx.x >> 6, lane = threadIdx.x & 63;
  const int bi = blockIdx.x * 4 + w;
  if (bi >= BATCH) return;
  const float* x = H + (size_t)bi * SEQ * DMODEL;
  const float x0 = x[lane], x1 = x[lane + 64], x2 = x[lane + 128];
  const float m = wredSum(x0 + x1 + x2) * (1.f / 192.f);
  const float d0 = x0 - m, d1 = x1 - m, d2 = x2 - m;
  const float v = wredSum(d0 * d0 + d1 * d1 + d2 * d2) * (1.f / 192.f);
  const float inv = rsqrtf(v + 1e-5f);
  float* y = out + (size_t)bi * DMODEL;
  y[lane] = d0 * inv * g[lane] + bta[lane];
  y[lane + 64] = d1 * inv * g[lane + 64] + bta[lane + 64];
  y[lane + 128] = d2 * inv * g[lane + 128] + bta[lane + 128];
}

// ---------------------------------------------------------------------------
// V^T: QKVbf bf16 -> Vt bf16 [b*3+h][64][SPAD], zero-padded keys
// ---------------------------------------------------------------------------
__global__ __launch_bounds__(256) void vtrans_kernel(const unsigned short* __restrict__ qkv,
                                                     unsigned short* __restrict__ vt) {
  const int bid = blockIdx.x;
  const int sc = bid & 3, bh = bid >> 2;
  const int b = bh / 3, h = bh % 3;
  const int s0 = sc * 64;
  __shared__ unsigned short t[64][72];
  const int tid = threadIdx.x;
  for (int e = tid; e < 64 * 64; e += 256) {
    const int sp = e >> 6, d = e & 63;
    const int s = s0 + sp;
    t[sp][d] = (s < SEQ) ? qkv[((size_t)(b * SEQ + s)) * 576 + 384 + h * 64 + d] : (unsigned short)0;
  }
  __syncthreads();
  for (int e = tid; e < 64 * 64; e += 256) {
    const int d = e >> 6, sp = e & 63;
    const int s = s0 + sp;
    if (s < SPAD) vt[((size_t)bh * 64 + d) * SPAD + s] = t[sp][d];
  }
}

// ---------------------------------------------------------------------------
// bf16 MFMA flash attention (QKV already bf16). One wave per (b,h,16-q tile).
// ---------------------------------------------------------------------------
__global__ __launch_bounds__(64) void attn_mfma_kernel(const unsigned short* __restrict__ qkv,
                                                       const unsigned short* __restrict__ vt,
                                                       unsigned short* __restrict__ out) {
  const int bid = blockIdx.x;
  const int bh = bid / 13, qt = bid % 13;
  const int b = bh / 3, h = bh % 3;
  const int row0 = b * SEQ;
  const int q0 = qt * 16;
  const int lane = threadIdx.x;
  const int c = lane & 15, g = lane >> 4;

  __shared__ __attribute__((aligned(16))) unsigned short P[16][232];

  const int qr = row0 + min(q0 + c, SEQ - 1);
  const unsigned short* qp = qkv + (size_t)qr * 576 + h * 64 + g * 8;
  const s16x8 qlo = *(const s16x8*)qp;
  const s16x8 qhi = *(const s16x8*)(qp + 32);

  f32x4 acc[13];
#pragma unroll
  for (int t = 0; t < 13; t++) {
    const int kr = row0 + min(t * 16 + c, SEQ - 1);
    const unsigned short* kp = qkv + (size_t)kr * 576 + 192 + h * 64 + g * 8;
    const s16x8 klo = *(const s16x8*)kp;
    const s16x8 khi = *(const s16x8*)(kp + 32);
    f32x4 z = {0.f, 0.f, 0.f, 0.f};
    z = __builtin_amdgcn_mfma_f32_16x16x32_bf16(qlo, klo, z, 0, 0, 0);
    acc[t] = __builtin_amdgcn_mfma_f32_16x16x32_bf16(qhi, khi, z, 0, 0, 0);
  }

  const bool m12 = (c >= 5);
#pragma unroll
  for (int r = 0; r < 4; r++) {
    float mx = -INFINITY;
#pragma unroll
    for (int t = 0; t < 13; t++) {
      const float v = (t == 12 && m12) ? -INFINITY : acc[t][r];
      mx = fmaxf(mx, v);
    }
#pragma unroll
    for (int o = 1; o <= 8; o <<= 1) mx = fmaxf(mx, __shfl_xor(mx, o, 64));
    const float ms = mx * 0.125f;
    float sum = 0.f;
#pragma unroll
    for (int t = 0; t < 13; t++) {
      const float e = (t == 12 && m12) ? 0.f : __expf(acc[t][r] * 0.125f - ms);
      acc[t][r] = e;
      sum += e;
    }
#pragma unroll
    for (int o = 1; o <= 8; o <<= 1) sum += __shfl_xor(sum, o, 64);
    const float inv = 1.f / sum;
#pragma unroll
    for (int t = 0; t < 13; t++) P[g * 4 + r][t * 16 + c] = f2bf(acc[t][r] * inv);
  }
  {
    unsigned short z4[4] = {0, 0, 0, 0};
    *(uint2*)&P[c][208 + g * 4] = *(uint2*)z4;
  }
  __builtin_amdgcn_s_waitcnt(0);

  f32x4 oacc[4];
#pragma unroll
  for (int dt = 0; dt < 4; dt++) oacc[dt] = (f32x4){0.f, 0.f, 0.f, 0.f};
  const unsigned short* vbase = vt + (size_t)bh * 64 * SPAD;
#pragma unroll
  for (int ch = 0; ch < 7; ch++) {
    const s16x8 pa = *(const s16x8*)&P[c][ch * 32 + g * 8];
#pragma unroll
    for (int dt = 0; dt < 4; dt++) {
      const s16x8 vb = *(const s16x8*)(vbase + (size_t)(dt * 16 + c) * SPAD + ch * 32 + g * 8);
      oacc[dt] = __builtin_amdgcn_mfma_f32_16x16x32_bf16(pa, vb, oacc[dt], 0, 0, 0);
    }
  }

#pragma unroll
  for (int dt = 0; dt < 4; dt++) {
#pragma unroll
    for (int r = 0; r < 4; r++) {
      const int q = q0 + g * 4 + r;
      if (q < SEQ) out[(size_t)(row0 + q) * DMODEL + h * 64 + dt * 16 + c] = f2bf(oacc[dt][r]);
    }
  }
}

// ---------------------------------------------------------------------------
extern "C" void kernel_launch(void* const* d_in, const int* in_sizes, int n_in,
                              void* d_out, int out_size, void* d_ws, size_t ws_size,
                              hipStream_t stream) {
  const float* x       = (const float*)d_in[0];
  const float* xg      = (const float*)d_in[1];
  const float* patch_w = (const float*)d_in[2];
  const float* patch_b = (const float*)d_in[3];
  const float* cls_tok = (const float*)d_in[4];
  const float* pos_emb = (const float*)d_in[5];
  const float* ele_emb = (const float*)d_in[6];
  const float* sat_wq  = (const float*)d_in[7];
  const float* sat_bq  = (const float*)d_in[8];
  const float* sat_wk  = (const float*)d_in[9];
  const float* sat_bk  = (const float*)d_in[10];
  const float* sat_wv  = (const float*)d_in[11];
  const float* sat_bv  = (const float*)d_in[12];
  const float* sat_wo  = (const float*)d_in[13];
  const float* sat_bo  = (const float*)d_in[14];
  const float* ln1_g   = (const float*)d_in[15];
  const float* ln1_b   = (const float*)d_in[16];
  const float* qkv_w   = (const float*)d_in[17];
  const float* qkv_b   = (const float*)d_in[18];
  const float* proj_w  = (const float*)d_in[19];
  const float* proj_b  = (const float*)d_in[20];
  const float* ln2_g   = (const float*)d_in[21];
  const float* ln2_b   = (const float*)d_in[22];
  const float* fc1_w   = (const float*)d_in[23];
  const float* fc1_b   = (const float*)d_in[24];
  const float* fc2_w   = (const float*)d_in[25];
  const float* fc2_b   = (const float*)d_in[26];
  const float* norm_g  = (const float*)d_in[27];
  const float* norm_b  = (const float*)d_in[28];
  float* out = (float*)d_out;
  float* ws = (float*)d_ws;

  // ---- workspace layout (float units) ----
  float* W_ELE = ws;                                   // 128
  float* EQ = ws + 256;
  float* EK = EQ + 32768;
  float* EV = EK + 32768;                              // ends 98560
  float* H = ws + 98560;                               // 25216*192 f32
  unsigned short* Hbf   = (unsigned short*)(ws + 4940032);
  unsigned short* Ybf   = (unsigned short*)(ws + 7360768);
  unsigned short* QKVbf = (unsigned short*)(ws + 9781504);
  unsigned short* MLPbf = (unsigned short*)(ws + 17043712);
  unsigned short* VTB   = (unsigned short*)(ws + 26726656);
  unsigned short* WTS   = (unsigned short*)(ws + 29479168);  // 5,652,480 shorts

  unsigned short* qkv_wt   = WTS;
  unsigned short* proj_wt  = WTS + 1327104;
  unsigned short* fc1_wt   = WTS + 1769472;
  unsigned short* fc2_wt   = WTS + 3538944;
  unsigned short* patch_bf = WTS + 5308416;
  unsigned short* satq_t   = WTS + 5455872;
  unsigned short* satk_t   = WTS + 5505024;
  unsigned short* satv_t   = WTS + 5554176;
  unsigned short* sato_t   = WTS + 5603328;

  // aliases (phases don't overlap)
  unsigned short* COLbf  = MLPbf;                       // 25088*768
  unsigned short* TOKRAW = Ybf;                         // 25088*192
  unsigned short* QTbf   = QKVbf;                       // 25216*256
  unsigned short* KTbf   = QKVbf + 6455296;
  unsigned short* VTbf   = MLPbf;
  unsigned short* O256bf = MLPbf + 6455296;

  // ---- weight conversion/transpose ----
  wtrans_kernel<<<dim3(18, 6, 12), 256, 0, stream>>>(qkv_w, qkv_wt, 192, 576);
  wtrans_kernel<<<dim3(6, 6, 12), 256, 0, stream>>>(proj_w, proj_wt, 192, 192);
  wtrans_kernel<<<dim3(24, 6, 12), 256, 0, stream>>>(fc1_w, fc1_wt, 192, 768);
  wtrans_kernel<<<dim3(6, 24, 12), 256, 0, stream>>>(fc2_w, fc2_wt, 768, 192);
  wtrans_kernel<<<dim3(8, 6, 1), 256, 0, stream>>>(sat_wq, satq_t, 192, 256);
  wtrans_kernel<<<dim3(8, 6, 1), 256, 0, stream>>>(sat_wk, satk_t, 192, 256);
  wtrans_kernel<<<dim3(8, 6, 1), 256, 0, stream>>>(sat_wv, satv_t, 192, 256);
  wtrans_kernel<<<dim3(6, 8, 1), 256, 0, stream>>>(sat_wo, sato_t, 256, 192);
  convert_kernel<<<144, 256, 0, stream>>>(patch_w, patch_bf, 36864);

  eleva_w_kernel<<<BATCH, 256, 0, stream>>>(xg, W_ELE);

  // ---- patch embed ----
  im2col_kernel<<<(MROWS_PATCH * KPATCH) / 256, 256, 0, stream>>>(x, COLbf);
  gemm_mfma<192, 0><<<dim3(3, 196), 256, 0, stream>>>(COLbf, patch_bf, patch_b, nullptr,
                                                      TOKRAW, MROWS_PATCH, DMODEL, KPATCH);
  assemble_kernel<<<(BS_ROWS * DMODEL) / 256, 256, 0, stream>>>(TOKRAW, cls_tok, pos_emb, H, Hbf);

  // ---- SAT fusion ----
  ele_proj_kernel<<<BATCH, 256, 0, stream>>>(ele_emb, sat_wq, sat_bq, sat_wk, sat_bk,
                                             sat_wv, sat_bv, W_ELE, EQ, EK, EV);
  gemm_mfma<192, 0><<<dim3(4, 197), 256, 0, stream>>>(Hbf, satq_t, sat_bq, nullptr, QTbf,
                                                      BS_ROWS, 256, DMODEL);
  gemm_mfma<192, 0><<<dim3(4, 197), 256, 0, stream>>>(Hbf, satk_t, sat_bk, nullptr, KTbf,
                                                      BS_ROWS, 256, DMODEL);
  gemm_mfma<192, 0><<<dim3(4, 197), 256, 0, stream>>>(Hbf, satv_t, sat_bv, nullptr, VTbf,
                                                      BS_ROWS, 256, DMODEL);
  sat_mix_kernel<<<BS_ROWS / 32, 256, 0, stream>>>(QTbf, KTbf, VTbf, EQ, EK, EV, O256bf);
  gemm_mfma<128, 3><<<dim3(3, 197), 256, 0, stream>>>(O256bf, sato_t, sat_bo, nullptr, H,
                                                      BS_ROWS, DMODEL, 256);

  // ---- 12 transformer blocks ----
  for (int l = 0; l < DEPTH; l++) {
    ln_kernel<<<BS_ROWS / 4, 256, 0, stream>>>(H, ln1_g + l * DMODEL, ln1_b + l * DMODEL, Ybf,
                                               BS_ROWS);
    gemm_mfma<192, 0><<<dim3(9, 197), 256, 0, stream>>>(
        Ybf, qkv_wt + (size_t)l * 110592, qkv_b + l * 576, nullptr, QKVbf, BS_ROWS, 576, DMODEL);
    vtrans_kernel<<<BATCH * 3 * 4, 256, 0, stream>>>(QKVbf, VTB);
    attn_mfma_kernel<<<BATCH * 3 * 13, 64, 0, stream>>>(QKVbf, VTB, Ybf);
    gemm_mfma<192, 2><<<dim3(3, 197), 256, 0, stream>>>(
        Ybf, proj_wt + (size_t)l * 36864, proj_b + l * DMODEL, H, H, BS_ROWS, DMODEL, DMODEL);
    ln_kernel<<<BS_ROWS / 4, 256, 0, stream>>>(H, ln2_g + l * DMODEL, ln2_b + l * DMODEL, Ybf,
                                               BS_ROWS);
    gemm_mfma<192, 1><<<dim3(12, 197), 256, 0, stream>>>(
        Ybf, fc1_wt + (size_t)l * 147456, fc1_b + l * MLPDIM, nullptr, MLPbf, BS_ROWS, MLPDIM,
        DMODEL);
    gemm_mfma<192, 2><<<dim3(3, 197), 256, 0, stream>>>(
        MLPbf, fc2_wt + (size_t)l * 147456, fc2_b + l * DMODEL, H, H, BS_ROWS, DMODEL, MLPDIM);
  }

  final_ln_kernel<<<BATCH / 4, 256, 0, stream>>>(H, norm_g, norm_b, out);
}

// Round 4
// 2002.187 us; speedup vs baseline: 5.8691x; 1.0046x over previous
//
#include <hip/hip_runtime.h>

// ---------------------------------------------------------------------------
// ViT-Tiny + SAT elevation fusion. bf16 MFMA GEMMs + bf16 MFMA flash attn.
// B=128, S=197, D=192, depth=12, heads=3 (hd=64), MLP=768.
// GEMM: BM=128 BN=96 BK=64 double-buffered 2-phase, wave tile 64x48.
// ---------------------------------------------------------------------------

#define BATCH 128
#define SEQ 197
#define BS_ROWS (BATCH * SEQ)          // 25216 = 197*128
#define DMODEL 192
#define NPATCH 196
#define MROWS_PATCH (BATCH * NPATCH)   // 25088 = 196*128
#define KPATCH 768
#define MLPDIM 768
#define DEPTH 12
#define SPAD 224

typedef float f32x4 __attribute__((ext_vector_type(4)));
typedef short s16x8 __attribute__((ext_vector_type(8)));

__device__ __forceinline__ float wredSum(float v) {
#pragma unroll
  for (int o = 32; o > 0; o >>= 1) v += __shfl_xor(v, o, 64);
  return v;
}

__device__ __forceinline__ unsigned short f2bf(float f) {
  union { float f; unsigned u; } v;
  v.f = f;
  unsigned r = v.u + 0x7FFFu + ((v.u >> 16) & 1u);  // RNE
  return (unsigned short)(r >> 16);
}
__device__ __forceinline__ float bf2f(unsigned short u) {
  union { unsigned u; float f; } v;
  v.u = ((unsigned)u) << 16;
  return v.f;
}

// ---------------------------------------------------------------------------
// Elevation weight
// ---------------------------------------------------------------------------
__global__ __launch_bounds__(256) void eleva_w_kernel(const float* __restrict__ xg,
                                                      float* __restrict__ wout) {
  const int b = blockIdx.x;
  const float* p = xg + (size_t)b * 3136;
  float s = 0.f;
  for (int i = threadIdx.x; i < 3136; i += 256) s += p[i];
  __shared__ float partial[4];
  s = wredSum(s);
  if ((threadIdx.x & 63) == 0) partial[threadIdx.x >> 6] = s;
  __syncthreads();
  if (threadIdx.x == 0) {
    float m = (partial[0] + partial[1] + partial[2] + partial[3]) / 3136.f;
    int idx = 0;
#pragma unroll
    for (int i = 0; i < 10; i++) {
      float pv = 0.1f * (float)(i + 1);
      if (pv < m) idx = i + 1;
    }
    if (idx > 9) idx = 9;
    float wv;
    if (idx == 9) {
      wv = 9.f;
    } else {
      float hi = 0.1f * (float)(idx + 1);
      float lo = (idx == 0) ? 0.f : 0.1f * (float)idx;
      wv = (float)idx - (hi - m) / (hi - lo);
    }
    wout[b] = wv / 10.f;
  }
}

// ---------------------------------------------------------------------------
// Weight transpose fp32 [R][C] -> bf16 [C][R]
// ---------------------------------------------------------------------------
__global__ __launch_bounds__(256) void wtrans_kernel(const float* __restrict__ in,
                                                     unsigned short* __restrict__ out,
                                                     int R, int C) {
  const int z = blockIdx.z;
  in += (size_t)z * R * C;
  out += (size_t)z * R * C;
  const int c0 = blockIdx.x * 32, r0 = blockIdx.y * 32;
  __shared__ float t[32][33];
  const int tr = threadIdx.x >> 3, tc = (threadIdx.x & 7) * 4;
  const float4 v = *(const float4*)(in + (size_t)(r0 + tr) * C + c0 + tc);
  t[tr][tc] = v.x; t[tr][tc + 1] = v.y; t[tr][tc + 2] = v.z; t[tr][tc + 3] = v.w;
  __syncthreads();
  ushort4 o;
  o.x = f2bf(t[tc + 0][tr]);
  o.y = f2bf(t[tc + 1][tr]);
  o.z = f2bf(t[tc + 2][tr]);
  o.w = f2bf(t[tc + 3][tr]);
  *(ushort4*)(out + (size_t)(c0 + tr) * R + r0 + tc) = o;
}

__global__ __launch_bounds__(256) void convert_kernel(const float* __restrict__ in,
                                                      unsigned short* __restrict__ out, int n4) {
  const int i = blockIdx.x * 256 + threadIdx.x;
  if (i >= n4) return;
  const float4 v = *(const float4*)(in + (size_t)i * 4);
  ushort4 o;
  o.x = f2bf(v.x); o.y = f2bf(v.y); o.z = f2bf(v.z); o.w = f2bf(v.w);
  *(ushort4*)(out + (size_t)i * 4) = o;
}

// ---------------------------------------------------------------------------
// im2col, 8 elems/thread (one half patch-row): float4 x2 in, 16B out
// ---------------------------------------------------------------------------
__global__ __launch_bounds__(256) void im2col_kernel(const float* __restrict__ x,
                                                     unsigned short* __restrict__ col) {
  const int i = blockIdx.x * 256 + threadIdx.x;  // index over 8-elem chunks
  if (i >= MROWS_PATCH * KPATCH / 8) return;
  const int k = (i % 96) * 8, row = i / 96;
  const int b = row / NPATCH, p = row % NPATCH;
  const int py = p / 14, px = p % 14;
  const int c = k >> 8, r = (k >> 4) & 15, cc = k & 15;
  const float* src = x + (((size_t)b * 3 + c) * 224 + (py * 16 + r)) * 224 + (px * 16 + cc);
  const float4 v0 = *(const float4*)src;
  const float4 v1 = *(const float4*)(src + 4);
  s16x8 o;
  o[0] = (short)f2bf(v0.x); o[1] = (short)f2bf(v0.y);
  o[2] = (short)f2bf(v0.z); o[3] = (short)f2bf(v0.w);
  o[4] = (short)f2bf(v1.x); o[5] = (short)f2bf(v1.y);
  o[6] = (short)f2bf(v1.z); o[7] = (short)f2bf(v1.w);
  *(s16x8*)(col + (size_t)i * 8) = o;
}

// cls row fill: H[b,0,:] = cls + pos[0]
__global__ __launch_bounds__(256) void cls_kernel(const float* __restrict__ cls,
                                                  const float* __restrict__ pos,
                                                  float* __restrict__ H,
                                                  unsigned short* __restrict__ Hbf) {
  const int i = blockIdx.x * 256 + threadIdx.x;
  if (i >= BATCH * DMODEL) return;
  const int b = i / DMODEL, d = i % DMODEL;
  const float v = cls[d] + pos[d];
  const size_t idx = (size_t)b * SEQ * DMODEL + d;
  H[idx] = v;
  Hbf[idx] = f2bf(v);
}

// ---------------------------------------------------------------------------
// SAT helpers
// ---------------------------------------------------------------------------
__global__ __launch_bounds__(256) void ele_proj_kernel(
    const float* __restrict__ ele_emb, const float* __restrict__ wq, const float* __restrict__ bq,
    const float* __restrict__ wk, const float* __restrict__ bk,
    const float* __restrict__ wv, const float* __restrict__ bv,
    const float* __restrict__ wvec, float* __restrict__ eq, float* __restrict__ ek,
    float* __restrict__ ev, float* __restrict__ satb) {
  const int b = blockIdx.x, t = threadIdx.x;
  if (b == 0) {  // concat bias for the merged SAT qkv GEMM
    satb[t] = bq[t];
    satb[256 + t] = bk[t];
    satb[512 + t] = bv[t];
  }
  __shared__ float es[DMODEL];
  if (t < DMODEL) es[t] = ele_emb[t] * wvec[b];
  __syncthreads();
  float aq = bq[t], ak = bk[t], av = bv[t];
  for (int d = 0; d < DMODEL; d++) {
    const float e = es[d];
    aq += e * wq[d * 256 + t];
    ak += e * wk[d * 256 + t];
    av += e * wv[d * 256 + t];
  }
  eq[b * 256 + t] = aq;
  ek[b * 256 + t] = ak;
  ev[b * 256 + t] = av;
}

// qkv768 rows: [q(256) | k(256) | v(256)]
__global__ __launch_bounds__(256) void sat_mix_kernel(
    const unsigned short* __restrict__ qkv768, const float* __restrict__ eq,
    const float* __restrict__ ek, const float* __restrict__ ev,
    unsigned short* __restrict__ o256) {
  const int gid = blockIdx.x * 256 + threadIdx.x;
  const int tok = gid >> 3, h = gid & 7;
  if (tok >= BS_ROWS) return;
  const int b = tok / SEQ;
  const unsigned short* qp = qkv768 + (size_t)tok * 768 + h * 32;
  const unsigned short* kp = qp + 256;
  const unsigned short* vp = qp + 512;
  const float* eqp = eq + b * 256 + h * 32;
  const float* ekp = ek + b * 256 + h * 32;
  const float* evp = ev + b * 256 + h * 32;
  float s00 = 0.f, s01 = 0.f, s10 = 0.f, s11 = 0.f;
#pragma unroll 8
  for (int d = 0; d < 32; d++) {
    const float q_ = bf2f(qp[d]), k_ = bf2f(kp[d]), eq_ = eqp[d], ek_ = ekp[d];
    s00 += q_ * k_;
    s01 += q_ * ek_;
    s10 += eq_ * k_;
    s11 += eq_ * ek_;
  }
  const float sc = 0.17677669529663687f;
  s00 *= sc; s01 *= sc; s10 *= sc; s11 *= sc;
  const float m0 = fmaxf(s00, s01), m1 = fmaxf(s10, s11);
  const float e00 = __expf(s00 - m0), e01 = __expf(s01 - m0);
  const float e10 = __expf(s10 - m1), e11 = __expf(s11 - m1);
  const float w0 = e00 / (e00 + e01) + e10 / (e10 + e11);
  const float w1 = e01 / (e00 + e01) + e11 / (e10 + e11);
  unsigned short* op = o256 + (size_t)tok * 256 + h * 32;
#pragma unroll 8
  for (int d = 0; d < 32; d++) op[d] = f2bf(w0 * bf2f(vp[d]) + w1 * evp[d]);
}

// ---------------------------------------------------------------------------
// bf16 MFMA GEMM. BM=128, BN=96, BK=64 double-buffered (2-phase pipeline:
// stage(next) -> compute(cur) -> one __syncthreads per K-step). 4 waves 2x2,
// wave tile 64x48 = 4x3 frags of 16x16x32. A [M][K] bf16, Bt [N][K] bf16.
// XOR slot swizzle (slot ^= row&7): inverse on global source, forward on
// ds_read; LDS dest linear (rule #21). Conflict-free b128 frag reads.
// EPI: 0 bias->bf16; 1 bias+gelu->bf16; 2 bias+res(f32)->f32; 3 2*bias->f32;
//      4 patch-assemble: (+bias+pos) -> H f32 + Hbf bf16 at shifted token row.
// Requires M%128==0, N%96==0, K%64==0.
// ---------------------------------------------------------------------------
template <int EPI>
__global__ __launch_bounds__(256) void gemm_mfma(const unsigned short* __restrict__ A,
                                                 const unsigned short* __restrict__ Bt,
                                                 const float* __restrict__ bias,
                                                 const float* __restrict__ res,
                                                 void* __restrict__ Cout,
                                                 unsigned short* __restrict__ aux_hbf,
                                                 const float* __restrict__ aux_pos,
                                                 int M, int N, int K) {
  __shared__ unsigned short As[2 * 128 * 64];  // 32 KB
  __shared__ unsigned short Bs[2 * 96 * 64];   // 24 KB
  const int tid = threadIdx.x, lane = tid & 63, w = tid >> 6;
  const int n0 = blockIdx.x * 96;
  const int m0 = blockIdx.y * 128;
  const int c = lane & 15, g = lane >> 4;
  const int wm = (w >> 1) * 64, wn = (w & 1) * 48;
  f32x4 acc[4][3] = {};

  auto stage = [&](int k0, int buf) {
    // A: wave w rows [w*32, w*32+32), 4 iters x 64 lanes x 16B
#pragma unroll
    for (int it = 0; it < 4; it++) {
      const int s = it * 64 + lane;
      const int r = w * 32 + (s >> 3);
      const int scol = (s & 7) ^ (r & 7);
      const unsigned short* gp = A + (size_t)(m0 + r) * K + k0 + scol * 8;
      __builtin_amdgcn_global_load_lds(
          (const __attribute__((address_space(1))) unsigned int*)gp,
          (__attribute__((address_space(3))) unsigned int*)(As + buf * 8192 + w * 2048 + it * 512),
          16, 0, 0);
    }
    // B: wave w rows [w*24, w*24+24), 3 iters
#pragma unroll
    for (int it = 0; it < 3; it++) {
      const int s = it * 64 + lane;
      const int r = w * 24 + (s >> 3);
      const int scol = (s & 7) ^ (r & 7);
      const unsigned short* gp = Bt + (size_t)(n0 + r) * K + k0 + scol * 8;
      __builtin_amdgcn_global_load_lds(
          (const __attribute__((address_space(1))) unsigned int*)gp,
          (__attribute__((address_space(3))) unsigned int*)(Bs + buf * 6144 + w * 1536 + it * 512),
          16, 0, 0);
    }
  };

  auto compute = [&](int buf) {
#pragma unroll
    for (int kk = 0; kk < 2; kk++) {
      const int sw = (((kk * 4 + g) ^ (c & 7))) << 3;
      s16x8 af[4], bfr[3];
#pragma unroll
      for (int i = 0; i < 4; i++)
        af[i] = *(const s16x8*)&As[buf * 8192 + (wm + i * 16 + c) * 64 + sw];
#pragma unroll
      for (int j = 0; j < 3; j++)
        bfr[j] = *(const s16x8*)&Bs[buf * 6144 + (wn + j * 16 + c) * 64 + sw];
#pragma unroll
      for (int i = 0; i < 4; i++)
#pragma unroll
        for (int j = 0; j < 3; j++)
          acc[i][j] = __builtin_amdgcn_mfma_f32_16x16x32_bf16(af[i], bfr[j], acc[i][j], 0, 0, 0);
    }
  };

  int cur = 0;
  stage(0, 0);
  __syncthreads();
  for (int k0 = 64; k0 < K; k0 += 64) {
    stage(k0, cur ^ 1);
    compute(cur);
    __syncthreads();
    cur ^= 1;
  }
  compute(cur);

  // --- epilogue ---
  const int ncol0 = n0 + wn + c;
  float bv[3];
#pragma unroll
  for (int j = 0; j < 3; j++) bv[j] = bias[ncol0 + j * 16] * (EPI == 3 ? 2.f : 1.f);
#pragma unroll
  for (int i = 0; i < 4; i++) {
#pragma unroll
    for (int r_ = 0; r_ < 4; r_++) {
      const int mrow = m0 + wm + i * 16 + g * 4 + r_;
      if (EPI == 4) {
        const int bb = mrow / 196;
        const int p = mrow - bb * 196;
        const size_t drow = (size_t)mrow + bb + 1;
#pragma unroll
        for (int j = 0; j < 3; j++) {
          const int col = ncol0 + j * 16;
          const float v = acc[i][j][r_] + bv[j] + aux_pos[(size_t)(p + 1) * DMODEL + col];
          const size_t idx = drow * DMODEL + col;
          ((float*)Cout)[idx] = v;
          aux_hbf[idx] = f2bf(v);
        }
      } else {
#pragma unroll
        for (int j = 0; j < 3; j++) {
          float v = acc[i][j][r_] + bv[j];
          const size_t idx = (size_t)mrow * N + ncol0 + j * 16;
          if (EPI == 0) {
            ((unsigned short*)Cout)[idx] = f2bf(v);
          } else if (EPI == 1) {
            v = 0.5f * v * (1.0f + erff(v * 0.70710678118654752f));
            ((unsigned short*)Cout)[idx] = f2bf(v);
          } else if (EPI == 2) {
            ((float*)Cout)[idx] = v + res[idx];
          } else {
            ((float*)Cout)[idx] = v;
          }
        }
      }
    }
  }
}

// ---------------------------------------------------------------------------
// LayerNorm: fp32 in -> bf16 out
// ---------------------------------------------------------------------------
__global__ __launch_bounds__(256) void ln_kernel(const float* __restrict__ X,
                                                 const float* __restrict__ g,
                                                 const float* __restrict__ bta,
                                                 unsigned short* __restrict__ Y, int nrows) {
  const int w = threadIdx.x >> 6, lane = threadIdx.x & 63;
  const int row = blockIdx.x * 4 + w;
  if (row >= nrows) return;
  const float* x = X + (size_t)row * DMODEL;
  const float x0 = x[lane], x1 = x[lane + 64], x2 = x[lane + 128];
  const float m = wredSum(x0 + x1 + x2) * (1.f / 192.f);
  const float d0 = x0 - m, d1 = x1 - m, d2 = x2 - m;
  const float v = wredSum(d0 * d0 + d1 * d1 + d2 * d2) * (1.f / 192.f);
  const float inv = rsqrtf(v + 1e-5f);
  unsigned short* y = Y + (size_t)row * DMODEL;
  y[lane] = f2bf(d0 * inv * g[lane] + bta[lane]);
  y[lane + 64] = f2bf(d1 * inv * g[lane + 64] + bta[lane + 64]);
  y[lane + 128] = f2bf(d2 * inv * g[lane + 128] + bta[lane + 128]);
}

__global__ __launch_bounds__(256) void final_ln_kernel(const float* __restrict__ H,
                                                       const float* __restrict__ g,
                                                       const float* __restrict__ bta,
                                                       float* __restrict__ out) {
  const int w = threadIdx.x >> 6, lane = threadIdx.x & 63;
  const int bi = blockIdx.x * 4 + w;
  if (bi >= BATCH) return;
  const float* x = H + (size_t)bi * SEQ * DMODEL;
  const float x0 = x[lane], x1 = x[lane + 64], x2 = x[lane + 128];
  const float m = wredSum(x0 + x1 + x2) * (1.f / 192.f);
  const float d0 = x0 - m, d1 = x1 - m, d2 = x2 - m;
  const float v = wredSum(d0 * d0 + d1 * d1 + d2 * d2) * (1.f / 192.f);
  const float inv = rsqrtf(v + 1e-5f);
  float* y = out + (size_t)bi * DMODEL;
  y[lane] = d0 * inv * g[lane] + bta[lane];
  y[lane + 64] = d1 * inv * g[lane + 64] + bta[lane + 64];
  y[lane + 128] = d2 * inv * g[lane + 128] + bta[lane + 128];
}

// ---------------------------------------------------------------------------
// V^T: QKVbf bf16 -> Vt bf16 [b*3+h][64][SPAD], zero-padded keys
// ---------------------------------------------------------------------------
__global__ __launch_bounds__(256) void vtrans_kernel(const unsigned short* __restrict__ qkv,
                                                     unsigned short* __restrict__ vt) {
  const int bid = blockIdx.x;
  const int sc = bid & 3, bh = bid >> 2;
  const int b = bh / 3, h = bh % 3;
  const int s0 = sc * 64;
  __shared__ unsigned short t[64][72];
  const int tid = threadIdx.x;
  for (int e = tid; e < 64 * 64; e += 256) {
    const int sp = e >> 6, d = e & 63;
    const int s = s0 + sp;
    t[sp][d] = (s < SEQ) ? qkv[((size_t)(b * SEQ + s)) * 576 + 384 + h * 64 + d] : (unsigned short)0;
  }
  __syncthreads();
  for (int e = tid; e < 64 * 64; e += 256) {
    const int d = e >> 6, sp = e & 63;
    const int s = s0 + sp;
    if (s < SPAD) vt[((size_t)bh * 64 + d) * SPAD + s] = t[sp][d];
  }
}

// ---------------------------------------------------------------------------
// bf16 MFMA flash attention. One wave per (b,h,16-q tile).
// ---------------------------------------------------------------------------
__global__ __launch_bounds__(64) void attn_mfma_kernel(const unsigned short* __restrict__ qkv,
                                                       const unsigned short* __restrict__ vt,
                                                       unsigned short* __restrict__ out) {
  const int bid = blockIdx.x;
  const int bh = bid / 13, qt = bid % 13;
  const int b = bh / 3, h = bh % 3;
  const int row0 = b * SEQ;
  const int q0 = qt * 16;
  const int lane = threadIdx.x;
  const int c = lane & 15, g = lane >> 4;

  __shared__ __attribute__((aligned(16))) unsigned short P[16][232];

  const int qr = row0 + min(q0 + c, SEQ - 1);
  const unsigned short* qp = qkv + (size_t)qr * 576 + h * 64 + g * 8;
  const s16x8 qlo = *(const s16x8*)qp;
  const s16x8 qhi = *(const s16x8*)(qp + 32);

  f32x4 acc[13];
#pragma unroll
  for (int t = 0; t < 13; t++) {
    const int kr = row0 + min(t * 16 + c, SEQ - 1);
    const unsigned short* kp = qkv + (size_t)kr * 576 + 192 + h * 64 + g * 8;
    const s16x8 klo = *(const s16x8*)kp;
    const s16x8 khi = *(const s16x8*)(kp + 32);
    f32x4 z = {0.f, 0.f, 0.f, 0.f};
    z = __builtin_amdgcn_mfma_f32_16x16x32_bf16(qlo, klo, z, 0, 0, 0);
    acc[t] = __builtin_amdgcn_mfma_f32_16x16x32_bf16(qhi, khi, z, 0, 0, 0);
  }

  const bool m12 = (c >= 5);
#pragma unroll
  for (int r = 0; r < 4; r++) {
    float mx = -INFINITY;
#pragma unroll
    for (int t = 0; t < 13; t++) {
      const float v = (t == 12 && m12) ? -INFINITY : acc[t][r];
      mx = fmaxf(mx, v);
    }
#pragma unroll
    for (int o = 1; o <= 8; o <<= 1) mx = fmaxf(mx, __shfl_xor(mx, o, 64));
    const float ms = mx * 0.125f;
    float sum = 0.f;
#pragma unroll
    for (int t = 0; t < 13; t++) {
      const float e = (t == 12 && m12) ? 0.f : __expf(acc[t][r] * 0.125f - ms);
      acc[t][r] = e;
      sum += e;
    }
#pragma unroll
    for (int o = 1; o <= 8; o <<= 1) sum += __shfl_xor(sum, o, 64);
    const float inv = 1.f / sum;
#pragma unroll
    for (int t = 0; t < 13; t++) P[g * 4 + r][t * 16 + c] = f2bf(acc[t][r] * inv);
  }
  {
    unsigned short z4[4] = {0, 0, 0, 0};
    *(uint2*)&P[c][208 + g * 4] = *(uint2*)z4;
  }
  __builtin_amdgcn_s_waitcnt(0);

  f32x4 oacc[4];
#pragma unroll
  for (int dt = 0; dt < 4; dt++) oacc[dt] = (f32x4){0.f, 0.f, 0.f, 0.f};
  const unsigned short* vbase = vt + (size_t)bh * 64 * SPAD;
#pragma unroll
  for (int ch = 0; ch < 7; ch++) {
    const s16x8 pa = *(const s16x8*)&P[c][ch * 32 + g * 8];
#pragma unroll
    for (int dt = 0; dt < 4; dt++) {
      const s16x8 vb = *(const s16x8*)(vbase + (size_t)(dt * 16 + c) * SPAD + ch * 32 + g * 8);
      oacc[dt] = __builtin_amdgcn_mfma_f32_16x16x32_bf16(pa, vb, oacc[dt], 0, 0, 0);
    }
  }

#pragma unroll
  for (int dt = 0; dt < 4; dt++) {
#pragma unroll
    for (int r = 0; r < 4; r++) {
      const int q = q0 + g * 4 + r;
      if (q < SEQ) out[(size_t)(row0 + q) * DMODEL + h * 64 + dt * 16 + c] = f2bf(oacc[dt][r]);
    }
  }
}

// ---------------------------------------------------------------------------
extern "C" void kernel_launch(void* const* d_in, const int* in_sizes, int n_in,
                              void* d_out, int out_size, void* d_ws, size_t ws_size,
                              hipStream_t stream) {
  const float* x       = (const float*)d_in[0];
  const float* xg      = (const float*)d_in[1];
  const float* patch_w = (const float*)d_in[2];
  const float* patch_b = (const float*)d_in[3];
  const float* cls_tok = (const float*)d_in[4];
  const float* pos_emb = (const float*)d_in[5];
  const float* ele_emb = (const float*)d_in[6];
  const float* sat_wq  = (const float*)d_in[7];
  const float* sat_bq  = (const float*)d_in[8];
  const float* sat_wk  = (const float*)d_in[9];
  const float* sat_bk  = (const float*)d_in[10];
  const float* sat_wv  = (const float*)d_in[11];
  const float* sat_bv  = (const float*)d_in[12];
  const float* sat_wo  = (const float*)d_in[13];
  const float* sat_bo  = (const float*)d_in[14];
  const float* ln1_g   = (const float*)d_in[15];
  const float* ln1_b   = (const float*)d_in[16];
  const float* qkv_w   = (const float*)d_in[17];
  const float* qkv_b   = (const float*)d_in[18];
  const float* proj_w  = (const float*)d_in[19];
  const float* proj_b  = (const float*)d_in[20];
  const float* ln2_g   = (const float*)d_in[21];
  const float* ln2_b   = (const float*)d_in[22];
  const float* fc1_w   = (const float*)d_in[23];
  const float* fc1_b   = (const float*)d_in[24];
  const float* fc2_w   = (const float*)d_in[25];
  const float* fc2_b   = (const float*)d_in[26];
  const float* norm_g  = (const float*)d_in[27];
  const float* norm_b  = (const float*)d_in[28];
  float* out = (float*)d_out;
  float* ws = (float*)d_ws;

  // ---- workspace layout (float units) ----
  float* W_ELE = ws;                                   // 128
  float* EQ = ws + 256;
  float* EK = EQ + 32768;
  float* EV = EK + 32768;                              // ends 98560
  float* H = ws + 98560;                               // 25216*192 f32
  unsigned short* Hbf   = (unsigned short*)(ws + 4940032);
  unsigned short* Ybf   = (unsigned short*)(ws + 7360768);
  unsigned short* QKVbf = (unsigned short*)(ws + 9781504);   // 25216*576
  unsigned short* MLPbf = (unsigned short*)(ws + 17043712);  // 25216*768
  unsigned short* VTB   = (unsigned short*)(ws + 26726656);
  unsigned short* WTS   = (unsigned short*)(ws + 29479168);  // 5,652,480 shorts
  float* SATB = ws + 32305408;                               // 768 floats

  unsigned short* qkv_wt   = WTS;
  unsigned short* proj_wt  = WTS + 1327104;
  unsigned short* fc1_wt   = WTS + 1769472;
  unsigned short* fc2_wt   = WTS + 3538944;
  unsigned short* patch_bf = WTS + 5308416;
  unsigned short* satqkv_t = WTS + 5455872;  // [q|k|v] each 256x192 -> 768x192
  unsigned short* sato_t   = WTS + 5603328;

  // aliases (phases don't overlap)
  unsigned short* COLbf   = MLPbf;            // 25088*768 (patch phase)
  unsigned short* SATQKV  = MLPbf;            // 25216*768 (SAT phase)
  unsigned short* O256bf  = QKVbf;            // 25216*256 (SAT phase)

  // ---- weight conversion/transpose ----
  wtrans_kernel<<<dim3(18, 6, 12), 256, 0, stream>>>(qkv_w, qkv_wt, 192, 576);
  wtrans_kernel<<<dim3(6, 6, 12), 256, 0, stream>>>(proj_w, proj_wt, 192, 192);
  wtrans_kernel<<<dim3(24, 6, 12), 256, 0, stream>>>(fc1_w, fc1_wt, 192, 768);
  wtrans_kernel<<<dim3(6, 24, 12), 256, 0, stream>>>(fc2_w, fc2_wt, 768, 192);
  wtrans_kernel<<<dim3(8, 6, 1), 256, 0, stream>>>(sat_wq, satqkv_t, 192, 256);
  wtrans_kernel<<<dim3(8, 6, 1), 256, 0, stream>>>(sat_wk, satqkv_t + 49152, 192, 256);
  wtrans_kernel<<<dim3(8, 6, 1), 256, 0, stream>>>(sat_wv, satqkv_t + 98304, 192, 256);
  wtrans_kernel<<<dim3(6, 8, 1), 256, 0, stream>>>(sat_wo, sato_t, 256, 192);
  convert_kernel<<<144, 256, 0, stream>>>(patch_w, patch_bf, 36864);

  eleva_w_kernel<<<BATCH, 256, 0, stream>>>(xg, W_ELE);

  // ---- patch embed (gemm fuses +pos and token-row shift; cls row separate) ----
  im2col_kernel<<<(MROWS_PATCH * KPATCH / 8) / 256, 256, 0, stream>>>(x, COLbf);
  gemm_mfma<4><<<dim3(2, 196), 256, 0, stream>>>(COLbf, patch_bf, patch_b, nullptr, H, Hbf,
                                                 pos_emb, MROWS_PATCH, DMODEL, KPATCH);
  cls_kernel<<<(BATCH * DMODEL) / 256, 256, 0, stream>>>(cls_tok, pos_emb, H, Hbf);

  // ---- SAT fusion (q,k,v merged into one N=768 GEMM) ----
  ele_proj_kernel<<<BATCH, 256, 0, stream>>>(ele_emb, sat_wq, sat_bq, sat_wk, sat_bk,
                                             sat_wv, sat_bv, W_ELE, EQ, EK, EV, SATB);
  gemm_mfma<0><<<dim3(8, 197), 256, 0, stream>>>(Hbf, satqkv_t, SATB, nullptr, SATQKV,
                                                 nullptr, nullptr, BS_ROWS, 768, DMODEL);
  sat_mix_kernel<<<BS_ROWS / 32, 256, 0, stream>>>(SATQKV, EQ, EK, EV, O256bf);
  gemm_mfma<3><<<dim3(2, 197), 256, 0, stream>>>(O256bf, sato_t, sat_bo, nullptr, H,
                                                 nullptr, nullptr, BS_ROWS, DMODEL, 256);

  // ---- 12 transformer blocks ----
  for (int l = 0; l < DEPTH; l++) {
    ln_kernel<<<BS_ROWS / 4, 256, 0, stream>>>(H, ln1_g + l * DMODEL, ln1_b + l * DMODEL, Ybf,
                                               BS_ROWS);
    gemm_mfma<0><<<dim3(6, 197), 256, 0, stream>>>(Ybf, qkv_wt + (size_t)l * 110592,
                                                   qkv_b + l * 576, nullptr, QKVbf, nullptr,
                                                   nullptr, BS_ROWS, 576, DMODEL);
    vtrans_kernel<<<BATCH * 3 * 4, 256, 0, stream>>>(QKVbf, VTB);
    attn_mfma_kernel<<<BATCH * 3 * 13, 64, 0, stream>>>(QKVbf, VTB, Ybf);
    gemm_mfma<2><<<dim3(2, 197), 256, 0, stream>>>(Ybf, proj_wt + (size_t)l * 36864,
                                                   proj_b + l * DMODEL, H, H, nullptr, nullptr,
                                                   BS_ROWS, DMODEL, DMODEL);
    ln_kernel<<<BS_ROWS / 4, 256, 0, stream>>>(H, ln2_g + l * DMODEL, ln2_b + l * DMODEL, Ybf,
                                               BS_ROWS);
    gemm_mfma<1><<<dim3(8, 197), 256, 0, stream>>>(Ybf, fc1_wt + (size_t)l * 147456,
                                                   fc1_b + l * MLPDIM, nullptr, MLPbf, nullptr,
                                                   nullptr, BS_ROWS, MLPDIM, DMODEL);
    gemm_mfma<2><<<dim3(2, 197), 256, 0, stream>>>(MLPbf, fc2_wt + (size_t)l * 147456,
                                                   fc2_b + l * DMODEL, H, H, nullptr, nullptr,
                                                   BS_ROWS, DMODEL, MLPDIM);
  }

  final_ln_kernel<<<BATCH / 4, 256, 0, stream>>>(H, norm_g, norm_b, out);
}

// Round 5
// 1819.210 us; speedup vs baseline: 6.4594x; 1.1006x over previous
//
#include <hip/hip_runtime.h>

// ---------------------------------------------------------------------------
// ViT-Tiny + SAT elevation fusion. bf16 MFMA GEMMs + bf16 MFMA flash attn.
// B=128, S=197, D=192, depth=12, heads=3 (hd=64), MLP=768.
// KEY: all GEMM A-operands and weights are stored PRE-SWIZZLED in global
// (16B slot s of row r at slot s^(r&7) within each aligned 8-slot group), so
// global_load_lds staging is linear/coalesced and ds_read_b128 is
// conflict-free. Producers write the permuted column (free, scalar writes).
// ---------------------------------------------------------------------------

#define BATCH 128
#define SEQ 197
#define BS_ROWS (BATCH * SEQ)          // 25216 = 197*128
#define DMODEL 192
#define NPATCH 196
#define MROWS_PATCH (BATCH * NPATCH)   // 25088 = 196*128
#define KPATCH 768
#define MLPDIM 768
#define DEPTH 12
#define SPAD 224

typedef float f32x4 __attribute__((ext_vector_type(4)));
typedef short s16x8 __attribute__((ext_vector_type(8)));

__device__ __forceinline__ float wredSum(float v) {
#pragma unroll
  for (int o = 32; o > 0; o >>= 1) v += __shfl_xor(v, o, 64);
  return v;
}

__device__ __forceinline__ unsigned short f2bf(float f) {
  union { float f; unsigned u; } v;
  v.f = f;
  unsigned r = v.u + 0x7FFFu + ((v.u >> 16) & 1u);  // RNE
  return (unsigned short)(r >> 16);
}
__device__ __forceinline__ float bf2f(unsigned short u) {
  union { unsigned u; float f; } v;
  v.u = ((unsigned)u) << 16;
  return v.f;
}

// column permutation for pre-swizzled GEMM-A / weight tensors
__device__ __forceinline__ int swz(int col, int row) {
  int g8 = col >> 3;
  g8 = (g8 & ~7) | ((g8 & 7) ^ (row & 7));
  return (g8 << 3) | (col & 7);
}

// exact-GELU via A&S 7.1.26 rational erf (|eps| <= 1.5e-7)
__device__ __forceinline__ float gelu(float x) {
  const float ax = fabsf(x) * 0.70710678118654752f;
  const float t = 1.f / (1.f + 0.3275911f * ax);
  const float y =
      t * (0.254829592f +
           t * (-0.284496736f +
                t * (1.421413741f + t * (-1.453152027f + t * 1.061405429f))));
  const float erfc_ = y * __expf(-ax * ax);
  const float cdf = (x >= 0.f) ? (1.f - 0.5f * erfc_) : (0.5f * erfc_);
  return x * cdf;
}

// ---------------------------------------------------------------------------
// Elevation weight
// ---------------------------------------------------------------------------
__global__ __launch_bounds__(256) void eleva_w_kernel(const float* __restrict__ xg,
                                                      float* __restrict__ wout) {
  const int b = blockIdx.x;
  const float* p = xg + (size_t)b * 3136;
  float s = 0.f;
  for (int i = threadIdx.x; i < 3136; i += 256) s += p[i];
  __shared__ float partial[4];
  s = wredSum(s);
  if ((threadIdx.x & 63) == 0) partial[threadIdx.x >> 6] = s;
  __syncthreads();
  if (threadIdx.x == 0) {
    float m = (partial[0] + partial[1] + partial[2] + partial[3]) / 3136.f;
    int idx = 0;
#pragma unroll
    for (int i = 0; i < 10; i++) {
      float pv = 0.1f * (float)(i + 1);
      if (pv < m) idx = i + 1;
    }
    if (idx > 9) idx = 9;
    float wv;
    if (idx == 9) {
      wv = 9.f;
    } else {
      float hi = 0.1f * (float)(idx + 1);
      float lo = (idx == 0) ? 0.f : 0.1f * (float)idx;
      wv = (float)idx - (hi - m) / (hi - lo);
    }
    wout[b] = wv / 10.f;
  }
}

// ---------------------------------------------------------------------------
// Weight transpose fp32 [R][C] -> bf16 [C][R], output PRE-SWIZZLED
// (B-row = c0+tr, K-col = r0+tc)
// ---------------------------------------------------------------------------
__global__ __launch_bounds__(256) void wtrans_kernel(const float* __restrict__ in,
                                                     unsigned short* __restrict__ out,
                                                     int R, int C) {
  const int z = blockIdx.z;
  in += (size_t)z * R * C;
  out += (size_t)z * R * C;
  const int c0 = blockIdx.x * 32, r0 = blockIdx.y * 32;
  __shared__ float t[32][33];
  const int tr = threadIdx.x >> 3, tc = (threadIdx.x & 7) * 4;
  const float4 v = *(const float4*)(in + (size_t)(r0 + tr) * C + c0 + tc);
  t[tr][tc] = v.x; t[tr][tc + 1] = v.y; t[tr][tc + 2] = v.z; t[tr][tc + 3] = v.w;
  __syncthreads();
  ushort4 o;
  o.x = f2bf(t[tc + 0][tr]);
  o.y = f2bf(t[tc + 1][tr]);
  o.z = f2bf(t[tc + 2][tr]);
  o.w = f2bf(t[tc + 3][tr]);
  const int brow = c0 + tr;
  *(ushort4*)(out + (size_t)brow * R + swz(r0 + tc, brow)) = o;
}

// fp32 [N][K] -> bf16 pre-swizzled (patch_w is [192][768])
__global__ __launch_bounds__(256) void convert_kernel(const float* __restrict__ in,
                                                      unsigned short* __restrict__ out, int n4,
                                                      int K) {
  const int i = blockIdx.x * 256 + threadIdx.x;
  if (i >= n4) return;
  const int flat = i * 4;
  const int row = flat / K, col = flat % K;
  const float4 v = *(const float4*)(in + flat);
  ushort4 o;
  o.x = f2bf(v.x); o.y = f2bf(v.y); o.z = f2bf(v.z); o.w = f2bf(v.w);
  *(ushort4*)(out + (size_t)row * K + swz(col, row)) = o;
}

// ---------------------------------------------------------------------------
// im2col, 8 elems/thread, output chunk placed at swizzled slot
// ---------------------------------------------------------------------------
__global__ __launch_bounds__(256) void im2col_kernel(const float* __restrict__ x,
                                                     unsigned short* __restrict__ col) {
  const int i = blockIdx.x * 256 + threadIdx.x;  // 8-elem chunks
  if (i >= MROWS_PATCH * KPATCH / 8) return;
  const int k = (i % 96) * 8, row = i / 96;
  const int b = row / NPATCH, p = row % NPATCH;
  const int py = p / 14, px = p % 14;
  const int c = k >> 8, r = (k >> 4) & 15, cc = k & 15;
  const float* src = x + (((size_t)b * 3 + c) * 224 + (py * 16 + r)) * 224 + (px * 16 + cc);
  const float4 v0 = *(const float4*)src;
  const float4 v1 = *(const float4*)(src + 4);
  s16x8 o;
  o[0] = (short)f2bf(v0.x); o[1] = (short)f2bf(v0.y);
  o[2] = (short)f2bf(v0.z); o[3] = (short)f2bf(v0.w);
  o[4] = (short)f2bf(v1.x); o[5] = (short)f2bf(v1.y);
  o[6] = (short)f2bf(v1.z); o[7] = (short)f2bf(v1.w);
  *(s16x8*)(col + (size_t)row * KPATCH + swz(k, row)) = o;
}

// cls row fill: H[b,0,:] = cls + pos[0]; Hbf swizzled (row = b*197)
__global__ __launch_bounds__(256) void cls_kernel(const float* __restrict__ cls,
                                                  const float* __restrict__ pos,
                                                  float* __restrict__ H,
                                                  unsigned short* __restrict__ Hbf) {
  const int i = blockIdx.x * 256 + threadIdx.x;
  if (i >= BATCH * DMODEL) return;
  const int b = i / DMODEL, d = i % DMODEL;
  const float v = cls[d] + pos[d];
  const int row = b * SEQ;
  H[(size_t)row * DMODEL + d] = v;
  Hbf[(size_t)row * DMODEL + swz(d, row)] = f2bf(v);
}

// ---------------------------------------------------------------------------
// SAT helpers
// ---------------------------------------------------------------------------
__global__ __launch_bounds__(256) void ele_proj_kernel(
    const float* __restrict__ ele_emb, const float* __restrict__ wq, const float* __restrict__ bq,
    const float* __restrict__ wk, const float* __restrict__ bk,
    const float* __restrict__ wv, const float* __restrict__ bv,
    const float* __restrict__ wvec, float* __restrict__ eq, float* __restrict__ ek,
    float* __restrict__ ev, float* __restrict__ satb) {
  const int b = blockIdx.x, t = threadIdx.x;
  if (b == 0) {
    satb[t] = bq[t];
    satb[256 + t] = bk[t];
    satb[512 + t] = bv[t];
  }
  __shared__ float es[DMODEL];
  if (t < DMODEL) es[t] = ele_emb[t] * wvec[b];
  __syncthreads();
  float aq = bq[t], ak = bk[t], av = bv[t];
  for (int d = 0; d < DMODEL; d++) {
    const float e = es[d];
    aq += e * wq[d * 256 + t];
    ak += e * wk[d * 256 + t];
    av += e * wv[d * 256 + t];
  }
  eq[b * 256 + t] = aq;
  ek[b * 256 + t] = ak;
  ev[b * 256 + t] = av;
}

// qkv768 rows: [q(256)|k(256)|v(256)] (linear); output O256 PRE-SWIZZLED
__global__ __launch_bounds__(256) void sat_mix_kernel(
    const unsigned short* __restrict__ qkv768, const float* __restrict__ eq,
    const float* __restrict__ ek, const float* __restrict__ ev,
    unsigned short* __restrict__ o256) {
  const int gid = blockIdx.x * 256 + threadIdx.x;
  const int tok = gid >> 3, h = gid & 7;
  if (tok >= BS_ROWS) return;
  const int b = tok / SEQ;
  const unsigned short* qp = qkv768 + (size_t)tok * 768 + h * 32;
  const unsigned short* kp = qp + 256;
  const unsigned short* vp = qp + 512;
  const float* eqp = eq + b * 256 + h * 32;
  const float* ekp = ek + b * 256 + h * 32;
  const float* evp = ev + b * 256 + h * 32;
  float s00 = 0.f, s01 = 0.f, s10 = 0.f, s11 = 0.f;
#pragma unroll 8
  for (int d = 0; d < 32; d++) {
    const float q_ = bf2f(qp[d]), k_ = bf2f(kp[d]), eq_ = eqp[d], ek_ = ekp[d];
    s00 += q_ * k_;
    s01 += q_ * ek_;
    s10 += eq_ * k_;
    s11 += eq_ * ek_;
  }
  const float sc = 0.17677669529663687f;
  s00 *= sc; s01 *= sc; s10 *= sc; s11 *= sc;
  const float m0 = fmaxf(s00, s01), m1 = fmaxf(s10, s11);
  const float e00 = __expf(s00 - m0), e01 = __expf(s01 - m0);
  const float e10 = __expf(s10 - m1), e11 = __expf(s11 - m1);
  const float w0 = e00 / (e00 + e01) + e10 / (e10 + e11);
  const float w1 = e01 / (e00 + e01) + e11 / (e10 + e11);
  unsigned short* op = o256 + (size_t)tok * 256;
#pragma unroll 8
  for (int d = 0; d < 32; d++)
    op[swz(h * 32 + d, tok)] = f2bf(w0 * bf2f(vp[d]) + w1 * evp[d]);
}

// ---------------------------------------------------------------------------
// bf16 MFMA GEMM, m97-style: BM=128, BN=96, BK=64, single LDS buffer (28 KB),
// stage -> barrier -> compute -> barrier. 4 waves 2x2, wave tile 64x48.
// A [M][K] bf16 PRE-SWIZZLED, Bt [N][K] bf16 PRE-SWIZZLED.
// Staging is LINEAR global_load_lds (coalesced); ds_read applies the forward
// swizzle -> conflict-free b128 (2-way max).
// EPI: 0 bias->bf16; 1 bias+gelu->bf16; 2 bias+res(f32)->f32; 3 2*bias->f32;
//      4 patch-assemble (+bias+pos) -> H f32 + Hbf bf16(swz) at shifted row.
// SWZO: swizzle output columns (when C feeds another GEMM as A).
// ---------------------------------------------------------------------------
template <int EPI, bool SWZO>
__global__ __launch_bounds__(256, 4) void gemm_mfma(const unsigned short* __restrict__ A,
                                                    const unsigned short* __restrict__ Bt,
                                                    const float* __restrict__ bias,
                                                    const float* __restrict__ res,
                                                    void* __restrict__ Cout,
                                                    unsigned short* __restrict__ aux_hbf,
                                                    const float* __restrict__ aux_pos,
                                                    int M, int N, int K) {
  __shared__ unsigned short As[128 * 64];  // 16 KB
  __shared__ unsigned short Bs[96 * 64];   // 12 KB
  const int tid = threadIdx.x, lane = tid & 63, w = tid >> 6;
  const int n0 = blockIdx.x * 96;
  const int m0 = blockIdx.y * 128;
  const int c = lane & 15, g = lane >> 4;
  const int wm = (w >> 1) * 64, wn = (w & 1) * 48;
  f32x4 acc[4][3] = {};

  const int ar = (lane >> 3);          // 0..7 row-in-group
  const int acol = (lane & 7) * 8;     // short offset of 16B slot

  for (int k0 = 0; k0 < K; k0 += 64) {
    // --- stage A: wave w rows [w*32, w*32+32), linear ---
#pragma unroll
    for (int it = 0; it < 4; it++) {
      const int r = w * 32 + it * 8 + ar;
      const unsigned short* gp = A + (size_t)(m0 + r) * K + k0 + acol;
      __builtin_amdgcn_global_load_lds(
          (const __attribute__((address_space(1))) unsigned int*)gp,
          (__attribute__((address_space(3))) unsigned int*)(As + w * 2048 + it * 512),
          16, 0, 0);
    }
    // --- stage B: wave w rows [w*24, w*24+24), linear ---
#pragma unroll
    for (int it = 0; it < 3; it++) {
      const int r = w * 24 + it * 8 + ar;
      const unsigned short* gp = Bt + (size_t)(n0 + r) * K + k0 + acol;
      __builtin_amdgcn_global_load_lds(
          (const __attribute__((address_space(1))) unsigned int*)gp,
          (__attribute__((address_space(3))) unsigned int*)(Bs + w * 1536 + it * 512),
          16, 0, 0);
    }
    __syncthreads();
    // --- compute (data in LDS is swizzled; forward-swizzled reads) ---
#pragma unroll
    for (int kk = 0; kk < 2; kk++) {
      const int sw = (((kk * 4 + g) ^ (c & 7))) << 3;
      s16x8 af[4], bfr[3];
#pragma unroll
      for (int i = 0; i < 4; i++)
        af[i] = *(const s16x8*)&As[(wm + i * 16 + c) * 64 + sw];
#pragma unroll
      for (int j = 0; j < 3; j++)
        bfr[j] = *(const s16x8*)&Bs[(wn + j * 16 + c) * 64 + sw];
#pragma unroll
      for (int i = 0; i < 4; i++)
#pragma unroll
        for (int j = 0; j < 3; j++)
          acc[i][j] = __builtin_amdgcn_mfma_f32_16x16x32_bf16(af[i], bfr[j], acc[i][j], 0, 0, 0);
    }
    __syncthreads();
  }

  // --- epilogue: C row = m0+wm+i*16+g*4+r_, col = n0+wn+j*16+c ---
  const int ncol0 = n0 + wn + c;
  float bv[3];
#pragma unroll
  for (int j = 0; j < 3; j++) bv[j] = bias[ncol0 + j * 16] * (EPI == 3 ? 2.f : 1.f);
#pragma unroll
  for (int i = 0; i < 4; i++) {
#pragma unroll
    for (int r_ = 0; r_ < 4; r_++) {
      const int mrow = m0 + wm + i * 16 + g * 4 + r_;
      if (EPI == 4) {
        const int bb = mrow / 196;
        const int p = mrow - bb * 196;
        const int drow = mrow + bb + 1;
#pragma unroll
        for (int j = 0; j < 3; j++) {
          const int col = ncol0 + j * 16;
          const float v = acc[i][j][r_] + bv[j] + aux_pos[(size_t)(p + 1) * DMODEL + col];
          ((float*)Cout)[(size_t)drow * DMODEL + col] = v;
          aux_hbf[(size_t)drow * DMODEL + swz(col, drow)] = f2bf(v);
        }
      } else {
#pragma unroll
        for (int j = 0; j < 3; j++) {
          float v = acc[i][j][r_] + bv[j];
          const int col = ncol0 + j * 16;
          const size_t rowoff = (size_t)mrow * N;
          if (EPI == 0) {
            ((unsigned short*)Cout)[rowoff + (SWZO ? swz(col, mrow) : col)] = f2bf(v);
          } else if (EPI == 1) {
            ((unsigned short*)Cout)[rowoff + (SWZO ? swz(col, mrow) : col)] = f2bf(gelu(v));
          } else if (EPI == 2) {
            ((float*)Cout)[rowoff + col] = v + res[rowoff + col];
          } else {
            ((float*)Cout)[rowoff + col] = v;
          }
        }
      }
    }
  }
}

// ---------------------------------------------------------------------------
// LayerNorm: fp32 in -> bf16 out, swizzled columns (feeds GEMM A)
// ---------------------------------------------------------------------------
__global__ __launch_bounds__(256) void ln_kernel(const float* __restrict__ X,
                                                 const float* __restrict__ g,
                                                 const float* __restrict__ bta,
                                                 unsigned short* __restrict__ Y, int nrows) {
  const int w = threadIdx.x >> 6, lane = threadIdx.x & 63;
  const int row = blockIdx.x * 4 + w;
  if (row >= nrows) return;
  const float* x = X + (size_t)row * DMODEL;
  const float x0 = x[lane], x1 = x[lane + 64], x2 = x[lane + 128];
  const float m = wredSum(x0 + x1 + x2) * (1.f / 192.f);
  const float d0 = x0 - m, d1 = x1 - m, d2 = x2 - m;
  const float v = wredSum(d0 * d0 + d1 * d1 + d2 * d2) * (1.f / 192.f);
  const float inv = rsqrtf(v + 1e-5f);
  unsigned short* y = Y + (size_t)row * DMODEL;
  y[swz(lane, row)] = f2bf(d0 * inv * g[lane] + bta[lane]);
  y[swz(lane + 64, row)] = f2bf(d1 * inv * g[lane + 64] + bta[lane + 64]);
  y[swz(lane + 128, row)] = f2bf(d2 * inv * g[lane + 128] + bta[lane + 128]);
}

__global__ __launch_bounds__(256) void final_ln_kernel(const float* __restrict__ H,
                                                       const float* __restrict__ g,
                                                       const float* __restrict__ bta,
                                                       float* __restrict__ out) {
  const int w = threadIdx.x >> 6, lane = threadIdx.x & 63;
  const int bi = blockIdx.x * 4 + w;
  if (bi >= BATCH) return;
  const float* x = H + (size_t)bi * SEQ * DMODEL;
  const float x0 = x[lane], x1 = x[lane + 64], x2 = x[lane + 128];
  const float m = wredSum(x0 + x1 + x2) * (1.f / 192.f);
  const float d0 = x0 - m, d1 = x1 - m, d2 = x2 - m;
  const float v = wredSum(d0 * d0 + d1 * d1 + d2 * d2) * (1.f / 192.f);
  const float inv = rsqrtf(v + 1e-5f);
  float* y = out + (size_t)bi * DMODEL;
  y[lane] = d0 * inv * g[lane] + bta[lane];
  y[lane + 64] = d1 * inv * g[lane + 64] + bta[lane + 64];
  y[lane + 128] = d2 * inv * g[lane + 128] + bta[lane + 128];
}

// ---------------------------------------------------------------------------
// V^T: QKVbf bf16 (linear) -> Vt bf16 [b*3+h][64][SPAD], zero-padded keys
// ---------------------------------------------------------------------------
__global__ __launch_bounds__(256) void vtrans_kernel(const unsigned short* __restrict__ qkv,
                                                     unsigned short* __restrict__ vt) {
  const int bid = blockIdx.x;
  const int sc = bid & 3, bh = bid >> 2;
  const int b = bh / 3, h = bh % 3;
  const int s0 = sc * 64;
  __shared__ unsigned short t[64][72];
  const int tid = threadIdx.x;
  for (int e = tid; e < 64 * 64; e += 256) {
    const int sp = e >> 6, d = e & 63;
    const int s = s0 + sp;
    t[sp][d] = (s < SEQ) ? qkv[((size_t)(b * SEQ + s)) * 576 + 384 + h * 64 + d] : (unsigned short)0;
  }
  __syncthreads();
  for (int e = tid; e < 64 * 64; e += 256) {
    const int d = e >> 6, sp = e & 63;
    const int s = s0 + sp;
    if (s < SPAD) vt[((size_t)bh * 64 + d) * SPAD + s] = t[sp][d];
  }
}

// ---------------------------------------------------------------------------
// bf16 MFMA flash attention. One wave per (b,h,16-q tile).
// Output written SWIZZLED (feeds proj GEMM as A).
// ---------------------------------------------------------------------------
__global__ __launch_bounds__(64) void attn_mfma_kernel(const unsigned short* __restrict__ qkv,
                                                       const unsigned short* __restrict__ vt,
                                                       unsigned short* __restrict__ out) {
  const int bid = blockIdx.x;
  const int bh = bid / 13, qt = bid % 13;
  const int b = bh / 3, h = bh % 3;
  const int row0 = b * SEQ;
  const int q0 = qt * 16;
  const int lane = threadIdx.x;
  const int c = lane & 15, g = lane >> 4;

  __shared__ __attribute__((aligned(16))) unsigned short P[16][232];

  const int qr = row0 + min(q0 + c, SEQ - 1);
  const unsigned short* qp = qkv + (size_t)qr * 576 + h * 64 + g * 8;
  const s16x8 qlo = *(const s16x8*)qp;
  const s16x8 qhi = *(const s16x8*)(qp + 32);

  f32x4 acc[13];
#pragma unroll
  for (int t = 0; t < 13; t++) {
    const int kr = row0 + min(t * 16 + c, SEQ - 1);
    const unsigned short* kp = qkv + (size_t)kr * 576 + 192 + h * 64 + g * 8;
    const s16x8 klo = *(const s16x8*)kp;
    const s16x8 khi = *(const s16x8*)(kp + 32);
    f32x4 z = {0.f, 0.f, 0.f, 0.f};
    z = __builtin_amdgcn_mfma_f32_16x16x32_bf16(qlo, klo, z, 0, 0, 0);
    acc[t] = __builtin_amdgcn_mfma_f32_16x16x32_bf16(qhi, khi, z, 0, 0, 0);
  }

  const bool m12 = (c >= 5);
#pragma unroll
  for (int r = 0; r < 4; r++) {
    float mx = -INFINITY;
#pragma unroll
    for (int t = 0; t < 13; t++) {
      const float v = (t == 12 && m12) ? -INFINITY : acc[t][r];
      mx = fmaxf(mx, v);
    }
#pragma unroll
    for (int o = 1; o <= 8; o <<= 1) mx = fmaxf(mx, __shfl_xor(mx, o, 64));
    const float ms = mx * 0.125f;
    float sum = 0.f;
#pragma unroll
    for (int t = 0; t < 13; t++) {
      const float e = (t == 12 && m12) ? 0.f : __expf(acc[t][r] * 0.125f - ms);
      acc[t][r] = e;
      sum += e;
    }
#pragma unroll
    for (int o = 1; o <= 8; o <<= 1) sum += __shfl_xor(sum, o, 64);
    const float inv = 1.f / sum;
#pragma unroll
    for (int t = 0; t < 13; t++) P[g * 4 + r][t * 16 + c] = f2bf(acc[t][r] * inv);
  }
  {
    unsigned short z4[4] = {0, 0, 0, 0};
    *(uint2*)&P[c][208 + g * 4] = *(uint2*)z4;
  }
  __builtin_amdgcn_s_waitcnt(0);

  f32x4 oacc[4];
#pragma unroll
  for (int dt = 0; dt < 4; dt++) oacc[dt] = (f32x4){0.f, 0.f, 0.f, 0.f};
  const unsigned short* vbase = vt + (size_t)bh * 64 * SPAD;
#pragma unroll
  for (int ch = 0; ch < 7; ch++) {
    const s16x8 pa = *(const s16x8*)&P[c][ch * 32 + g * 8];
#pragma unroll
    for (int dt = 0; dt < 4; dt++) {
      const s16x8 vb = *(const s16x8*)(vbase + (size_t)(dt * 16 + c) * SPAD + ch * 32 + g * 8);
      oacc[dt] = __builtin_amdgcn_mfma_f32_16x16x32_bf16(pa, vb, oacc[dt], 0, 0, 0);
    }
  }

#pragma unroll
  for (int dt = 0; dt < 4; dt++) {
#pragma unroll
    for (int r = 0; r < 4; r++) {
      const int q = q0 + g * 4 + r;
      if (q < SEQ) {
        const int trow = row0 + q;
        out[(size_t)trow * DMODEL + swz(h * 64 + dt * 16 + c, trow)] = f2bf(oacc[dt][r]);
      }
    }
  }
}

// ---------------------------------------------------------------------------
extern "C" void kernel_launch(void* const* d_in, const int* in_sizes, int n_in,
                              void* d_out, int out_size, void* d_ws, size_t ws_size,
                              hipStream_t stream) {
  const float* x       = (const float*)d_in[0];
  const float* xg      = (const float*)d_in[1];
  const float* patch_w = (const float*)d_in[2];
  const float* patch_b = (const float*)d_in[3];
  const float* cls_tok = (const float*)d_in[4];
  const float* pos_emb = (const float*)d_in[5];
  const float* ele_emb = (const float*)d_in[6];
  const float* sat_wq  = (const float*)d_in[7];
  const float* sat_bq  = (const float*)d_in[8];
  const float* sat_wk  = (const float*)d_in[9];
  const float* sat_bk  = (const float*)d_in[10];
  const float* sat_wv  = (const float*)d_in[11];
  const float* sat_bv  = (const float*)d_in[12];
  const float* sat_wo  = (const float*)d_in[13];
  const float* sat_bo  = (const float*)d_in[14];
  const float* ln1_g   = (const float*)d_in[15];
  const float* ln1_b   = (const float*)d_in[16];
  const float* qkv_w   = (const float*)d_in[17];
  const float* qkv_b   = (const float*)d_in[18];
  const float* proj_w  = (const float*)d_in[19];
  const float* proj_b  = (const float*)d_in[20];
  const float* ln2_g   = (const float*)d_in[21];
  const float* ln2_b   = (const float*)d_in[22];
  const float* fc1_w   = (const float*)d_in[23];
  const float* fc1_b   = (const float*)d_in[24];
  const float* fc2_w   = (const float*)d_in[25];
  const float* fc2_b   = (const float*)d_in[26];
  const float* norm_g  = (const float*)d_in[27];
  const float* norm_b  = (const float*)d_in[28];
  float* out = (float*)d_out;
  float* ws = (float*)d_ws;

  // ---- workspace layout (float units) ----
  float* W_ELE = ws;                                   // 128
  float* EQ = ws + 256;
  float* EK = EQ + 32768;
  float* EV = EK + 32768;                              // ends 98560
  float* H = ws + 98560;                               // 25216*192 f32
  unsigned short* Hbf   = (unsigned short*)(ws + 4940032);
  unsigned short* Ybf   = (unsigned short*)(ws + 7360768);
  unsigned short* QKVbf = (unsigned short*)(ws + 9781504);   // 25216*576
  unsigned short* MLPbf = (unsigned short*)(ws + 17043712);  // 25216*768
  unsigned short* VTB   = (unsigned short*)(ws + 26726656);
  unsigned short* WTS   = (unsigned short*)(ws + 29479168);  // 5,652,480 shorts
  float* SATB = ws + 32305408;                               // 768 floats

  unsigned short* qkv_wt   = WTS;
  unsigned short* proj_wt  = WTS + 1327104;
  unsigned short* fc1_wt   = WTS + 1769472;
  unsigned short* fc2_wt   = WTS + 3538944;
  unsigned short* patch_bf = WTS + 5308416;
  unsigned short* satqkv_t = WTS + 5455872;  // [q|k|v] each 256x192 -> 768x192
  unsigned short* sato_t   = WTS + 5603328;

  // aliases (phases don't overlap)
  unsigned short* COLbf   = MLPbf;            // 25088*768 (patch phase)
  unsigned short* SATQKV  = MLPbf;            // 25216*768 (SAT phase)
  unsigned short* O256bf  = QKVbf;            // 25216*256 (SAT phase)

  // ---- weight conversion/transpose (all pre-swizzled) ----
  wtrans_kernel<<<dim3(18, 6, 12), 256, 0, stream>>>(qkv_w, qkv_wt, 192, 576);
  wtrans_kernel<<<dim3(6, 6, 12), 256, 0, stream>>>(proj_w, proj_wt, 192, 192);
  wtrans_kernel<<<dim3(24, 6, 12), 256, 0, stream>>>(fc1_w, fc1_wt, 192, 768);
  wtrans_kernel<<<dim3(6, 24, 12), 256, 0, stream>>>(fc2_w, fc2_wt, 768, 192);
  wtrans_kernel<<<dim3(8, 6, 1), 256, 0, stream>>>(sat_wq, satqkv_t, 192, 256);
  wtrans_kernel<<<dim3(8, 6, 1), 256, 0, stream>>>(sat_wk, satqkv_t + 49152, 192, 256);
  wtrans_kernel<<<dim3(8, 6, 1), 256, 0, stream>>>(sat_wv, satqkv_t + 98304, 192, 256);
  wtrans_kernel<<<dim3(6, 8, 1), 256, 0, stream>>>(sat_wo, sato_t, 256, 192);
  convert_kernel<<<144, 256, 0, stream>>>(patch_w, patch_bf, 36864, KPATCH);

  eleva_w_kernel<<<BATCH, 256, 0, stream>>>(xg, W_ELE);

  // ---- patch embed (gemm fuses +pos and token-row shift; cls row separate) ----
  im2col_kernel<<<(MROWS_PATCH * KPATCH / 8) / 256, 256, 0, stream>>>(x, COLbf);
  gemm_mfma<4, false><<<dim3(2, 196), 256, 0, stream>>>(COLbf, patch_bf, patch_b, nullptr, H,
                                                        Hbf, pos_emb, MROWS_PATCH, DMODEL,
                                                        KPATCH);
  cls_kernel<<<(BATCH * DMODEL) / 256, 256, 0, stream>>>(cls_tok, pos_emb, H, Hbf);

  // ---- SAT fusion (q,k,v merged into one N=768 GEMM) ----
  ele_proj_kernel<<<BATCH, 256, 0, stream>>>(ele_emb, sat_wq, sat_bq, sat_wk, sat_bk,
                                             sat_wv, sat_bv, W_ELE, EQ, EK, EV, SATB);
  gemm_mfma<0, false><<<dim3(8, 197), 256, 0, stream>>>(Hbf, satqkv_t, SATB, nullptr, SATQKV,
                                                        nullptr, nullptr, BS_ROWS, 768, DMODEL);
  sat_mix_kernel<<<BS_ROWS / 32, 256, 0, stream>>>(SATQKV, EQ, EK, EV, O256bf);
  gemm_mfma<3, false><<<dim3(2, 197), 256, 0, stream>>>(O256bf, sato_t, sat_bo, nullptr, H,
                                                        nullptr, nullptr, BS_ROWS, DMODEL, 256);

  // ---- 12 transformer blocks ----
  for (int l = 0; l < DEPTH; l++) {
    ln_kernel<<<BS_ROWS / 4, 256, 0, stream>>>(H, ln1_g + l * DMODEL, ln1_b + l * DMODEL, Ybf,
                                               BS_ROWS);
    gemm_mfma<0, false><<<dim3(6, 197), 256, 0, stream>>>(Ybf, qkv_wt + (size_t)l * 110592,
                                                          qkv_b + l * 576, nullptr, QKVbf,
                                                          nullptr, nullptr, BS_ROWS, 576,
                                                          DMODEL);
    vtrans_kernel<<<BATCH * 3 * 4, 256, 0, stream>>>(QKVbf, VTB);
    attn_mfma_kernel<<<BATCH * 3 * 13, 64, 0, stream>>>(QKVbf, VTB, Ybf);
    gemm_mfma<2, false><<<dim3(2, 197), 256, 0, stream>>>(Ybf, proj_wt + (size_t)l * 36864,
                                                          proj_b + l * DMODEL, H, H, nullptr,
                                                          nullptr, BS_ROWS, DMODEL, DMODEL);
    ln_kernel<<<BS_ROWS / 4, 256, 0, stream>>>(H, ln2_g + l * DMODEL, ln2_b + l * DMODEL, Ybf,
                                               BS_ROWS);
    gemm_mfma<1, true><<<dim3(8, 197), 256, 0, stream>>>(Ybf, fc1_wt + (size_t)l * 147456,
                                                         fc1_b + l * MLPDIM, nullptr, MLPbf,
                                                         nullptr, nullptr, BS_ROWS, MLPDIM,
                                                         DMODEL);
    gemm_mfma<2, false><<<dim3(2, 197), 256, 0, stream>>>(MLPbf, fc2_wt + (size_t)l * 147456,
                                                          fc2_b + l * DMODEL, H, H, nullptr,
                                                          nullptr, BS_ROWS, DMODEL, MLPDIM);
  }

  final_ln_kernel<<<BATCH / 4, 256, 0, stream>>>(H, norm_g, norm_b, out);
}